// Round 1
// baseline (510.527 us; speedup 1.0000x reference)
//
#include <hip/hip_runtime.h>
#include <stdint.h>

typedef unsigned short u16;
typedef short bf16x8 __attribute__((ext_vector_type(8)));
typedef float f32x4 __attribute__((ext_vector_type(4)));

#define GLOAD_LDS16(gptr, lptr)                                                \
  __builtin_amdgcn_global_load_lds(                                            \
      (__attribute__((address_space(1))) void*)(gptr),                         \
      (__attribute__((address_space(3))) void*)(lptr), 16, 0, 0)

__device__ __forceinline__ u16 f2bf(float f) {
  union { float f; uint32_t u; } v; v.f = f;
  return (u16)((v.u + 0x7fffu + ((v.u >> 16) & 1u)) >> 16);
}
__device__ __forceinline__ float bf2f(u16 h) {
  union { uint32_t u; float f; } v; v.u = ((uint32_t)h) << 16;
  return v.f;
}

// ---------------- convert x (f32 -> bf16), 8 elems/thread ----------------
__global__ void k_conv_bf16(const float* __restrict__ src, u16* __restrict__ dst, int n8) {
  int i = blockIdx.x * blockDim.x + threadIdx.x;
  if (i >= n8) return;
  const float4* s = (const float4*)src + (size_t)i * 2;
  float4 a = s[0], b = s[1];
  uint4 o;
  o.x = (uint32_t)f2bf(a.x) | ((uint32_t)f2bf(a.y) << 16);
  o.y = (uint32_t)f2bf(a.z) | ((uint32_t)f2bf(a.w) << 16);
  o.z = (uint32_t)f2bf(b.x) | ((uint32_t)f2bf(b.y) << 16);
  o.w = (uint32_t)f2bf(b.z) | ((uint32_t)f2bf(b.w) << 16);
  ((uint4*)dst)[i] = o;
}

// ---------------- transpose f32 [R][C] -> bf16 [C][R] ----------------
__global__ void k_transpose_bf16(const float* __restrict__ src, u16* __restrict__ dst,
                                 int R, int C) {
  __shared__ float tile[32][33];
  int cb = blockIdx.x * 32, rb = blockIdx.y * 32;
  int tx = threadIdx.x, ty = threadIdx.y;
#pragma unroll
  for (int j = 0; j < 4; ++j)
    tile[ty + j * 8][tx] = src[(size_t)(rb + ty + j * 8) * C + cb + tx];
  __syncthreads();
#pragma unroll
  for (int j = 0; j < 4; ++j)
    dst[(size_t)(cb + ty + j * 8) * R + rb + tx] = f2bf(tile[tx][ty + j * 8]);
}

// ---------------- GEMM: C[M,N] = A[M,K] @ Bt[N,K]^T + bias ----------------
// 128x128 tile, BK=32, 4 waves (2x2), 16x16x32 bf16 MFMA.
// LDS chunk (row, j) holds global k-chunk j ^ ((row>>1)&3)  (bank-conflict swizzle,
// applied on the GLOBAL source so global_load_lds dest stays linear — rule #21).
template <bool BF16OUT>
__global__ __launch_bounds__(256) void k_gemm_bt(
    const u16* __restrict__ A, const u16* __restrict__ Bt,
    const float* __restrict__ bias, void* __restrict__ Cptr,
    int M, int N, int K) {
  __shared__ u16 As[128 * 32];
  __shared__ u16 Bs[128 * 32];
  const int t = threadIdx.x;
  const int lane = t & 63;
  const int w = t >> 6, wr = w >> 1, wc = w & 1;
  const int brow = blockIdx.y * 128, bcol = blockIdx.x * 128;
  const int g = lane >> 4, q = lane & 15;

  f32x4 acc[4][4] = {};
  const int srow = t >> 2;  // 0..63
  const int sj = t & 3;
  const int nkt = K >> 5;
  for (int kt = 0; kt < nkt; ++kt) {
    __syncthreads();
#pragma unroll
    for (int i = 0; i < 2; ++i) {
      int row = srow + i * 64;
      int jsrc = sj ^ ((row >> 1) & 3);
      const u16* ga = A + (size_t)(brow + row) * K + kt * 32 + jsrc * 8;
      const u16* gb = Bt + (size_t)(bcol + row) * K + kt * 32 + jsrc * 8;
      GLOAD_LDS16(ga, (char*)As + i * 4096 + t * 16);
      GLOAD_LDS16(gb, (char*)Bs + i * 4096 + t * 16);
    }
    __syncthreads();
    bf16x8 a[4], b[4];
#pragma unroll
    for (int mt = 0; mt < 4; ++mt) {
      int row = wr * 64 + mt * 16 + q;
      int pos = g ^ ((row >> 1) & 3);
      a[mt] = *(const bf16x8*)(As + row * 32 + pos * 8);
    }
#pragma unroll
    for (int nt = 0; nt < 4; ++nt) {
      int row = wc * 64 + nt * 16 + q;
      int pos = g ^ ((row >> 1) & 3);
      b[nt] = *(const bf16x8*)(Bs + row * 32 + pos * 8);
    }
#pragma unroll
    for (int mt = 0; mt < 4; ++mt)
#pragma unroll
      for (int nt = 0; nt < 4; ++nt)
        acc[mt][nt] = __builtin_amdgcn_mfma_f32_16x16x32_bf16(a[mt], b[nt], acc[mt][nt], 0, 0, 0);
  }
  // epilogue: D layout col=lane&15, row=(lane>>4)*4+reg  [m89-verified]
#pragma unroll
  for (int nt = 0; nt < 4; ++nt) {
    int col = bcol + wc * 64 + nt * 16 + q;
    float bv_ = bias[col];
#pragma unroll
    for (int mt = 0; mt < 4; ++mt) {
#pragma unroll
      for (int r = 0; r < 4; ++r) {
        int row = brow + wr * 64 + mt * 16 + g * 4 + r;
        float val = acc[mt][nt][r] + bv_;
        if (BF16OUT)
          ((u16*)Cptr)[(size_t)row * N + col] = f2bf(val);
        else
          ((float*)Cptr)[(size_t)row * N + col] = val;
      }
    }
  }
}

// ---------------- flash attention ----------------
// Block = 4 waves; wave w owns 16 q-rows. K/V tiles of 64 rows iterated over S.
// qkv layout: [4096][3072] bf16, cols 0..2047 = Q (h*64+d), 2048..2559 = K, 2560..3071 = V.
#define LOG2E 1.44269504088896340736f
__global__ __launch_bounds__(256) void k_attn(const u16* __restrict__ qkv,
                                              u16* __restrict__ out) {
  const int qt = blockIdx.x, h = blockIdx.y, b = blockIdx.z;
  const int kvh = h >> 2;
  const int t = threadIdx.x, lane = t & 63, w = t >> 6;
  const int g = lane >> 4, q = lane & 15;
  const int LDQ = 3072;

  __shared__ u16 Ksh[64 * 64];      // [k][d], chunk (row,j) holds dc = j ^ (row&7)
  __shared__ u16 Vsh[64 * 64];      // [d][k], chunk (d,kc) at kc ^ (d&7)
  __shared__ u16 Psh[4][16 * 72];   // per-wave P, padded stride 72

  // Q fragments (scaled by 1/sqrt(64) = 0.125 — exact in bf16)
  const size_t qrow = (size_t)(b * 2048 + qt * 64 + w * 16 + q);
  bf16x8 qf[2];
#pragma unroll
  for (int c = 0; c < 2; ++c) {
    bf16x8 tmp = *(const bf16x8*)(qkv + qrow * LDQ + h * 64 + c * 32 + g * 8);
#pragma unroll
    for (int i = 0; i < 8; ++i)
      tmp[i] = (short)f2bf(bf2f((u16)tmp[i]) * 0.125f);
    qf[c] = tmp;
  }

  f32x4 acc[4] = {};
  float m_run[4], l_run[4];
#pragma unroll
  for (int r = 0; r < 4; ++r) { m_run[r] = -__builtin_inff(); l_run[r] = 0.f; }

  const int kbase = b * 2048;
  for (int kt = 0; kt < 32; ++kt) {
    __syncthreads();
    // stage K via global_load_lds, source-swizzled
#pragma unroll
    for (int p = 0; p < 2; ++p) {
      int row = (t >> 3) + p * 32;
      int dc = (t & 7) ^ (row & 7);
      const u16* gk = qkv + (size_t)(kbase + kt * 64 + row) * LDQ + 2048 + kvh * 64 + dc * 8;
      GLOAD_LDS16(gk, (char*)Ksh + p * 4096 + t * 16);
    }
    // stage V transposed: lane k = t&63 -> conflict-free b16 writes
#pragma unroll
    for (int p = 0; p < 2; ++p) {
      int kk = t & 63;
      int dc = (t >> 6) + p * 4;
      bf16x8 vv = *(const bf16x8*)(qkv + (size_t)(kbase + kt * 64 + kk) * LDQ + 2560 + kvh * 64 + dc * 8);
#pragma unroll
      for (int i = 0; i < 8; ++i) {
        int d = dc * 8 + i;
        Vsh[d * 64 + (((kk >> 3) ^ (d & 7)) << 3) + (kk & 7)] = (u16)vv[i];
      }
    }
    __syncthreads();

    // scores: D[q][kcol], lane holds q-rows g*4+r, kcols nt*16+q
    f32x4 sc[4];
#pragma unroll
    for (int nt = 0; nt < 4; ++nt) {
      f32x4 z = {0.f, 0.f, 0.f, 0.f};
      sc[nt] = z;
      int kcol = nt * 16 + q;
#pragma unroll
      for (int c = 0; c < 2; ++c) {
        int dci = c * 4 + g;
        bf16x8 kf = *(const bf16x8*)(Ksh + kcol * 64 + ((dci ^ (kcol & 7)) << 3));
        sc[nt] = __builtin_amdgcn_mfma_f32_16x16x32_bf16(qf[c], kf, sc[nt], 0, 0, 0);
      }
    }
    // wave-parallel online softmax (16-lane xor reductions)
    float ps[4][4];
#pragma unroll
    for (int r = 0; r < 4; ++r) {
      float mt_ = fmaxf(fmaxf(sc[0][r], sc[1][r]), fmaxf(sc[2][r], sc[3][r]));
#pragma unroll
      for (int off = 1; off < 16; off <<= 1)
        mt_ = fmaxf(mt_, __shfl_xor(mt_, off, 64));
      float mn = fmaxf(m_run[r], mt_);
      float alpha = exp2f((m_run[r] - mn) * LOG2E);
      float lt = 0.f;
#pragma unroll
      for (int nt = 0; nt < 4; ++nt) {
        float p_ = exp2f((sc[nt][r] - mn) * LOG2E);
        ps[nt][r] = p_;
        lt += p_;
      }
#pragma unroll
      for (int off = 1; off < 16; off <<= 1)
        lt += __shfl_xor(lt, off, 64);
      l_run[r] = l_run[r] * alpha + lt;
      m_run[r] = mn;
#pragma unroll
      for (int dt = 0; dt < 4; ++dt) acc[dt][r] *= alpha;
    }
    // P -> LDS (bf16), then read back as A-fragments
#pragma unroll
    for (int nt = 0; nt < 4; ++nt)
#pragma unroll
      for (int r = 0; r < 4; ++r)
        Psh[w][(g * 4 + r) * 72 + nt * 16 + q] = f2bf(ps[nt][r]);
    __syncthreads();
    bf16x8 pf[2];
#pragma unroll
    for (int c = 0; c < 2; ++c)
      pf[c] = *(const bf16x8*)(&Psh[w][q * 72 + c * 32 + g * 8]);
#pragma unroll
    for (int dt = 0; dt < 4; ++dt) {
      int d = dt * 16 + q;
#pragma unroll
      for (int c = 0; c < 2; ++c) {
        int kc = c * 4 + g;
        bf16x8 vf = *(const bf16x8*)(Vsh + d * 64 + ((kc ^ (d & 7)) << 3));
        acc[dt] = __builtin_amdgcn_mfma_f32_16x16x32_bf16(pf[c], vf, acc[dt], 0, 0, 0);
      }
    }
  }
  // epilogue: rows g*4+r, cols dt*16+q
#pragma unroll
  for (int r = 0; r < 4; ++r) {
    float inv = 1.0f / l_run[r];
    size_t orow = (size_t)(b * 2048 + qt * 64 + w * 16 + g * 4 + r);
#pragma unroll
    for (int dt = 0; dt < 4; ++dt)
      out[orow * 2048 + h * 64 + dt * 16 + q] = f2bf(acc[dt][r] * inv);
  }
}

// ---------------- launch ----------------
extern "C" void kernel_launch(void* const* d_in, const int* in_sizes, int n_in,
                              void* d_out, int out_size, void* d_ws, size_t ws_size,
                              hipStream_t stream) {
  const float* x  = (const float*)d_in[0];
  const float* Wq = (const float*)d_in[1];
  const float* bq = (const float*)d_in[2];
  const float* Wk = (const float*)d_in[3];
  const float* bk = (const float*)d_in[4];
  const float* Wv = (const float*)d_in[5];
  const float* bv = (const float*)d_in[6];
  const float* Wo = (const float*)d_in[7];
  const float* bo = (const float*)d_in[8];
  float* out = (float*)d_out;

  char* ws = (char*)d_ws;
  // offsets (bytes)
  u16*   xb    = (u16*)(ws + 0);               // 4096x2048 bf16   = 16 MB
  u16*   wqkvT = (u16*)(ws + 16777216);        // 3072x2048 bf16   = 12 MB
  u16*   woT   = (u16*)(ws + 29360128);        // 2048x2048 bf16   = 8 MB
  float* bqkv  = (float*)(ws + 37748736);      // 3072 f32
  u16*   cqkv  = (u16*)(ws + 37761024);        // 4096x3072 bf16   = 24 MB
  u16*   aout  = (u16*)(ws + 62926848);        // 4096x2048 bf16   = 16 MB
  (void)ws_size; (void)in_sizes; (void)n_in; (void)out_size;

  hipMemcpyAsync(bqkv, bq, 2048 * sizeof(float), hipMemcpyDeviceToDevice, stream);
  hipMemcpyAsync(bqkv + 2048, bk, 512 * sizeof(float), hipMemcpyDeviceToDevice, stream);
  hipMemcpyAsync(bqkv + 2560, bv, 512 * sizeof(float), hipMemcpyDeviceToDevice, stream);

  k_conv_bf16<<<4096, 256, 0, stream>>>(x, xb, 1048576);
  dim3 tb(32, 8);
  k_transpose_bf16<<<dim3(64, 64), tb, 0, stream>>>(Wq, wqkvT, 2048, 2048);
  k_transpose_bf16<<<dim3(16, 64), tb, 0, stream>>>(Wk, wqkvT + 2048 * 2048, 2048, 512);
  k_transpose_bf16<<<dim3(16, 64), tb, 0, stream>>>(Wv, wqkvT + 2560 * 2048, 2048, 512);
  k_transpose_bf16<<<dim3(64, 64), tb, 0, stream>>>(Wo, woT, 2048, 2048);

  k_gemm_bt<true><<<dim3(24, 32), 256, 0, stream>>>(xb, wqkvT, bqkv, cqkv, 4096, 3072, 2048);
  k_attn<<<dim3(32, 32, 2), 256, 0, stream>>>(cqkv, aout);
  k_gemm_bt<false><<<dim3(16, 32), 256, 0, stream>>>(aout, woT, bo, out, 4096, 2048, 2048);
}

// Round 3
// 407.930 us; speedup vs baseline: 1.2515x; 1.2515x over previous
//
#include <hip/hip_runtime.h>
#include <stdint.h>

typedef unsigned short u16;
typedef unsigned int u32;
typedef short bf16x8 __attribute__((ext_vector_type(8)));
typedef float f32x4 __attribute__((ext_vector_type(4)));
typedef u32 u32x2 __attribute__((ext_vector_type(2)));

#define GLOAD_LDS16(gptr, lptr)                                                \
  __builtin_amdgcn_global_load_lds(                                            \
      (__attribute__((address_space(1))) void*)(gptr),                         \
      (__attribute__((address_space(3))) void*)(lptr), 16, 0, 0)

#if __has_builtin(__builtin_amdgcn_exp2f)
#define EXP2F(x) __builtin_amdgcn_exp2f(x)
#else
#define EXP2F(x) exp2f(x)
#endif

__device__ __forceinline__ u16 f2bf(float f) {
  union { float f; uint32_t u; } v; v.f = f;
  return (u16)((v.u + 0x7fffu + ((v.u >> 16) & 1u)) >> 16);
}
__device__ __forceinline__ float bf2f(u16 h) {
  union { uint32_t u; float f; } v; v.u = ((uint32_t)h) << 16;
  return v.f;
}
__device__ __forceinline__ u32 cvt_pk_bf16(float lo, float hi) {
  u32 r;
  asm("v_cvt_pk_bf16_f32 %0, %1, %2" : "=v"(r) : "v"(lo), "v"(hi));
  return r;
}

// ---------------- convert x (f32 -> bf16), 8 elems/thread ----------------
__global__ void k_conv_bf16(const float* __restrict__ src, u16* __restrict__ dst, int n8) {
  int i = blockIdx.x * blockDim.x + threadIdx.x;
  if (i >= n8) return;
  const float4* s = (const float4*)src + (size_t)i * 2;
  float4 a = s[0], b = s[1];
  uint4 o;
  o.x = (uint32_t)f2bf(a.x) | ((uint32_t)f2bf(a.y) << 16);
  o.y = (uint32_t)f2bf(a.z) | ((uint32_t)f2bf(a.w) << 16);
  o.z = (uint32_t)f2bf(b.x) | ((uint32_t)f2bf(b.y) << 16);
  o.w = (uint32_t)f2bf(b.z) | ((uint32_t)f2bf(b.w) << 16);
  ((uint4*)dst)[i] = o;
}

// ---------------- transpose f32 [R][C] -> bf16 [C][R] ----------------
__global__ void k_transpose_bf16(const float* __restrict__ src, u16* __restrict__ dst,
                                 int R, int C) {
  __shared__ float tile[32][33];
  int cb = blockIdx.x * 32, rb = blockIdx.y * 32;
  int tx = threadIdx.x, ty = threadIdx.y;
#pragma unroll
  for (int j = 0; j < 4; ++j)
    tile[ty + j * 8][tx] = src[(size_t)(rb + ty + j * 8) * C + cb + tx];
  __syncthreads();
#pragma unroll
  for (int j = 0; j < 4; ++j)
    dst[(size_t)(cb + ty + j * 8) * R + rb + tx] = f2bf(tile[tx][ty + j * 8]);
}

// ---------------- GEMM: C[M,N] = A[M,K] @ Bt[N,K]^T + bias ----------------
template <bool BF16OUT>
__global__ __launch_bounds__(256) void k_gemm_bt(
    const u16* __restrict__ A, const u16* __restrict__ Bt,
    const float* __restrict__ bias, void* __restrict__ Cptr,
    int M, int N, int K) {
  __shared__ u16 As[128 * 32];
  __shared__ u16 Bs[128 * 32];
  const int t = threadIdx.x;
  const int lane = t & 63;
  const int w = t >> 6, wr = w >> 1, wc = w & 1;
  const int brow = blockIdx.y * 128, bcol = blockIdx.x * 128;
  const int g = lane >> 4, q = lane & 15;

  f32x4 acc[4][4] = {};
  const int srow = t >> 2;
  const int sj = t & 3;
  const int nkt = K >> 5;
  for (int kt = 0; kt < nkt; ++kt) {
    __syncthreads();
#pragma unroll
    for (int i = 0; i < 2; ++i) {
      int row = srow + i * 64;
      int jsrc = sj ^ ((row >> 1) & 3);
      const u16* ga = A + (size_t)(brow + row) * K + kt * 32 + jsrc * 8;
      const u16* gb = Bt + (size_t)(bcol + row) * K + kt * 32 + jsrc * 8;
      GLOAD_LDS16(ga, (char*)As + i * 4096 + t * 16);
      GLOAD_LDS16(gb, (char*)Bs + i * 4096 + t * 16);
    }
    __syncthreads();
    bf16x8 a[4], b[4];
#pragma unroll
    for (int mt = 0; mt < 4; ++mt) {
      int row = wr * 64 + mt * 16 + q;
      int pos = g ^ ((row >> 1) & 3);
      a[mt] = *(const bf16x8*)(As + row * 32 + pos * 8);
    }
#pragma unroll
    for (int nt = 0; nt < 4; ++nt) {
      int row = wc * 64 + nt * 16 + q;
      int pos = g ^ ((row >> 1) & 3);
      b[nt] = *(const bf16x8*)(Bs + row * 32 + pos * 8);
    }
#pragma unroll
    for (int mt = 0; mt < 4; ++mt)
#pragma unroll
      for (int nt = 0; nt < 4; ++nt)
        acc[mt][nt] = __builtin_amdgcn_mfma_f32_16x16x32_bf16(a[mt], b[nt], acc[mt][nt], 0, 0, 0);
  }
#pragma unroll
  for (int nt = 0; nt < 4; ++nt) {
    int col = bcol + wc * 64 + nt * 16 + q;
    float bv_ = bias[col];
#pragma unroll
    for (int mt = 0; mt < 4; ++mt) {
#pragma unroll
      for (int r = 0; r < 4; ++r) {
        int row = brow + wr * 64 + mt * 16 + g * 4 + r;
        float val = acc[mt][nt][r] + bv_;
        if (BF16OUT)
          ((u16*)Cptr)[(size_t)row * N + col] = f2bf(val);
        else
          ((float*)Cptr)[(size_t)row * N + col] = val;
      }
    }
  }
}

// ---------------- flash attention (swapped-QK softmax, 2 q-subtiles/wave) ----
// Block = 4 waves, 128 q rows (wave w, subtile s -> rows qt*128 + s*64 + w*16 + 0..15).
// qkv layout: [4096][3072] bf16, cols 0..2047 = Q, 2048..2559 = K, 2560..3071 = V.
#define LOG2E 1.44269504088896340736f
__global__ __launch_bounds__(256) void k_attn(const u16* __restrict__ qkv,
                                              u16* __restrict__ out) {
  const int qt = blockIdx.x, h = blockIdx.y, b = blockIdx.z;
  const int kvh = h >> 2;
  const int t = threadIdx.x, lane = t & 63, w = t >> 6;
  const int g = lane >> 4, q16 = lane & 15;
  const int LDQ = 3072;

  __shared__ u16 Ksh[64 * 64];   // [kv][d], chunk (row,j) holds dc = j ^ (row&7)
  __shared__ u16 Vsh[64 * 64];   // [d][k], chunk (d,kc) at kc ^ (d&7)  (round-1-verified)
  __shared__ u16 Psh[4][16 * 72] __attribute__((aligned(16)));

  // Q fragments, scaled by 1/8 (exact in bf16)
  bf16x8 qf[2][2];
#pragma unroll
  for (int sub = 0; sub < 2; ++sub) {
    const size_t qrow = (size_t)(b * 2048 + qt * 128 + sub * 64 + w * 16 + q16);
#pragma unroll
    for (int c = 0; c < 2; ++c) {
      bf16x8 tmp = *(const bf16x8*)(qkv + qrow * LDQ + h * 64 + c * 32 + g * 8);
#pragma unroll
      for (int i = 0; i < 8; ++i)
        tmp[i] = (short)f2bf(bf2f((u16)tmp[i]) * 0.125f);
      qf[sub][c] = tmp;
    }
  }

  f32x4 acc[2][4] = {};
  float m_run[2], l_run[2];
  m_run[0] = m_run[1] = -__builtin_inff();
  l_run[0] = l_run[1] = 0.f;

  const int kbase = b * 2048;
  const int koff = 2048 + kvh * 64;
  const int voff = 2560 + kvh * 64;

  for (int kt = 0; kt < 32; ++kt) {
    __syncthreads();
    // ---- stage K (source-XOR-swizzled, linear LDS dest) ----
#pragma unroll
    for (int p = 0; p < 2; ++p) {
      int row = (t >> 3) + p * 32;
      int dc8 = (t & 7) ^ (row & 7);
      const u16* gk = qkv + (size_t)(kbase + kt * 64 + row) * LDQ + koff + dc8 * 8;
      GLOAD_LDS16(gk, (char*)Ksh + p * 4096 + t * 16);
    }
    // ---- stage V transposed via register repack (round-1-verified layout) ----
#pragma unroll
    for (int p = 0; p < 2; ++p) {
      int kk = t & 63;
      int dc = (t >> 6) + p * 4;
      bf16x8 vv = *(const bf16x8*)(qkv + (size_t)(kbase + kt * 64 + kk) * LDQ + voff + dc * 8);
#pragma unroll
      for (int i = 0; i < 8; ++i) {
        int d = dc * 8 + i;
        Vsh[d * 64 + (((kk >> 3) ^ (d & 7)) << 3) + (kk & 7)] = (u16)vv[i];
      }
    }
    __syncthreads();

    // ---- QK^T swapped: sc = mfma(K, Q) -> row = kv (nt*16+g*4+r), col = q (l&15)
    f32x4 sc[2][4] = {};
#pragma unroll
    for (int c = 0; c < 2; ++c) {
#pragma unroll
      for (int nt = 0; nt < 4; ++nt) {
        int row = nt * 16 + q16;
        bf16x8 kf = *(const bf16x8*)(Ksh + row * 64 + (((c * 4 + g) ^ (row & 7)) << 3));
        sc[0][nt] = __builtin_amdgcn_mfma_f32_16x16x32_bf16(kf, qf[0][c], sc[0][nt], 0, 0, 0);
        sc[1][nt] = __builtin_amdgcn_mfma_f32_16x16x32_bf16(kf, qf[1][c], sc[1][nt], 0, 0, 0);
      }
    }

    bf16x8 pf[2][2];
#pragma unroll
    for (int sub = 0; sub < 2; ++sub) {
      // row max: per-lane 16 values all belong to q = l&15; 2-step cross-group reduce
      float mt_ = sc[sub][0][0];
#pragma unroll
      for (int nt = 0; nt < 4; ++nt)
#pragma unroll
        for (int r = 0; r < 4; ++r)
          mt_ = fmaxf(mt_, sc[sub][nt][r]);
      mt_ = fmaxf(mt_, __shfl_xor(mt_, 16, 64));
      mt_ = fmaxf(mt_, __shfl_xor(mt_, 32, 64));
      // defer-rescale: only touch acc when some row saw a new max
      if (__any(mt_ > m_run[sub])) {
        float mn = fmaxf(m_run[sub], mt_);
        float alpha = EXP2F((m_run[sub] - mn) * LOG2E);
        m_run[sub] = mn;
        l_run[sub] *= alpha;
#pragma unroll
        for (int r = 0; r < 4; ++r) {
          float ar = __shfl(alpha, g * 4 + r, 64);
#pragma unroll
          for (int dt = 0; dt < 4; ++dt) acc[sub][dt][r] *= ar;
        }
      }
      float mL = m_run[sub] * LOG2E;
      float lt = 0.f;
#pragma unroll
      for (int nt = 0; nt < 4; ++nt)
#pragma unroll
        for (int r = 0; r < 4; ++r) {
          float p_ = EXP2F(fmaf(sc[sub][nt][r], LOG2E, -mL));
          sc[sub][nt][r] = p_;
          lt += p_;
        }
      lt += __shfl_xor(lt, 16, 64);
      lt += __shfl_xor(lt, 32, 64);
      l_run[sub] += lt;
      // pack P -> LDS (per-wave buffer, same-wave DS in-order; no block barrier)
      u16* prow = &Psh[w][q16 * 72];
#pragma unroll
      for (int nt = 0; nt < 4; ++nt) {
        u32x2 pk;
        pk.x = cvt_pk_bf16(sc[sub][nt][0], sc[sub][nt][1]);
        pk.y = cvt_pk_bf16(sc[sub][nt][2], sc[sub][nt][3]);
        *(u32x2*)(prow + nt * 16 + g * 4) = pk;
      }
      pf[sub][0] = *(const bf16x8*)(&Psh[w][q16 * 72 + g * 8]);
      pf[sub][1] = *(const bf16x8*)(&Psh[w][q16 * 72 + 32 + g * 8]);
    }

    // ---- PV: vf from swizzled Vsh (round-1-verified read pattern) ----
#pragma unroll
    for (int c = 0; c < 2; ++c) {
      int kc = c * 4 + g;
#pragma unroll
      for (int dt = 0; dt < 4; ++dt) {
        int d = dt * 16 + q16;
        bf16x8 vf = *(const bf16x8*)(Vsh + d * 64 + ((kc ^ (d & 7)) << 3));
#pragma unroll
        for (int sub = 0; sub < 2; ++sub)
          acc[sub][dt] = __builtin_amdgcn_mfma_f32_16x16x32_bf16(pf[sub][c], vf, acc[sub][dt], 0, 0, 0);
      }
    }
  }

  // ---- epilogue: rows g*4+r, cols dt*16+q16 ----
#pragma unroll
  for (int sub = 0; sub < 2; ++sub)
#pragma unroll
    for (int r = 0; r < 4; ++r) {
      float linv = 1.0f / __shfl(l_run[sub], g * 4 + r, 64);
      size_t orow = (size_t)(b * 2048 + qt * 128 + sub * 64 + w * 16 + g * 4 + r);
#pragma unroll
      for (int dt = 0; dt < 4; ++dt)
        out[orow * 2048 + h * 64 + dt * 16 + q16] = f2bf(acc[sub][dt][r] * linv);
    }
}

// ---------------- launch ----------------
extern "C" void kernel_launch(void* const* d_in, const int* in_sizes, int n_in,
                              void* d_out, int out_size, void* d_ws, size_t ws_size,
                              hipStream_t stream) {
  const float* x  = (const float*)d_in[0];
  const float* Wq = (const float*)d_in[1];
  const float* bq = (const float*)d_in[2];
  const float* Wk = (const float*)d_in[3];
  const float* bk = (const float*)d_in[4];
  const float* Wv = (const float*)d_in[5];
  const float* bv = (const float*)d_in[6];
  const float* Wo = (const float*)d_in[7];
  const float* bo = (const float*)d_in[8];
  float* out = (float*)d_out;

  char* ws = (char*)d_ws;
  u16*   xb    = (u16*)(ws + 0);               // 4096x2048 bf16   = 16 MB
  u16*   wqkvT = (u16*)(ws + 16777216);        // 3072x2048 bf16   = 12 MB
  u16*   woT   = (u16*)(ws + 29360128);        // 2048x2048 bf16   = 8 MB
  float* bqkv  = (float*)(ws + 37748736);      // 3072 f32
  u16*   cqkv  = (u16*)(ws + 37761024);        // 4096x3072 bf16   = 24 MB
  u16*   aout  = (u16*)(ws + 62926848);        // 4096x2048 bf16   = 16 MB
  (void)ws_size; (void)in_sizes; (void)n_in; (void)out_size;

  hipMemcpyAsync(bqkv, bq, 2048 * sizeof(float), hipMemcpyDeviceToDevice, stream);
  hipMemcpyAsync(bqkv + 2048, bk, 512 * sizeof(float), hipMemcpyDeviceToDevice, stream);
  hipMemcpyAsync(bqkv + 2560, bv, 512 * sizeof(float), hipMemcpyDeviceToDevice, stream);

  k_conv_bf16<<<4096, 256, 0, stream>>>(x, xb, 1048576);
  dim3 tb(32, 8);
  k_transpose_bf16<<<dim3(64, 64), tb, 0, stream>>>(Wq, wqkvT, 2048, 2048);
  k_transpose_bf16<<<dim3(16, 64), tb, 0, stream>>>(Wk, wqkvT + 2048 * 2048, 2048, 512);
  k_transpose_bf16<<<dim3(16, 64), tb, 0, stream>>>(Wv, wqkvT + 2560 * 2048, 2048, 512);
  k_transpose_bf16<<<dim3(64, 64), tb, 0, stream>>>(Wo, woT, 2048, 2048);

  k_gemm_bt<true><<<dim3(24, 32), 256, 0, stream>>>(xb, wqkvT, bqkv, cqkv, 4096, 3072, 2048);
  k_attn<<<dim3(16, 32, 2), 256, 0, stream>>>(cqkv, aout);
  k_gemm_bt<false><<<dim3(16, 32), 256, 0, stream>>>(aout, woT, bo, out, 4096, 2048, 2048);
}

// Round 4
// 397.940 us; speedup vs baseline: 1.2829x; 1.0251x over previous
//
#include <hip/hip_runtime.h>
#include <stdint.h>

typedef unsigned short u16;
typedef unsigned int u32;
typedef short bf16x8 __attribute__((ext_vector_type(8)));
typedef float f32x4 __attribute__((ext_vector_type(4)));
typedef u32 u32x2 __attribute__((ext_vector_type(2)));

#define GLOAD_LDS16(gptr, lptr)                                                \
  __builtin_amdgcn_global_load_lds(                                            \
      (__attribute__((address_space(1))) void*)(gptr),                         \
      (__attribute__((address_space(3))) void*)(lptr), 16, 0, 0)

#if __has_builtin(__builtin_amdgcn_exp2f)
#define EXP2F(x) __builtin_amdgcn_exp2f(x)
#else
#define EXP2F(x) exp2f(x)
#endif

__device__ __forceinline__ u16 f2bf(float f) {
  union { float f; uint32_t u; } v; v.f = f;
  return (u16)((v.u + 0x7fffu + ((v.u >> 16) & 1u)) >> 16);
}
__device__ __forceinline__ float bf2f(u16 h) {
  union { uint32_t u; float f; } v; v.u = ((uint32_t)h) << 16;
  return v.f;
}
__device__ __forceinline__ u32 cvt_pk_bf16(float lo, float hi) {
  u32 r;
  asm("v_cvt_pk_bf16_f32 %0, %1, %2" : "=v"(r) : "v"(lo), "v"(hi));
  return r;
}

// ---------------- convert x (f32 -> bf16), 8 elems/thread ----------------
__global__ void k_conv_bf16(const float* __restrict__ src, u16* __restrict__ dst, int n8) {
  int i = blockIdx.x * blockDim.x + threadIdx.x;
  if (i >= n8) return;
  const float4* s = (const float4*)src + (size_t)i * 2;
  float4 a = s[0], b = s[1];
  uint4 o;
  o.x = (uint32_t)f2bf(a.x) | ((uint32_t)f2bf(a.y) << 16);
  o.y = (uint32_t)f2bf(a.z) | ((uint32_t)f2bf(a.w) << 16);
  o.z = (uint32_t)f2bf(b.x) | ((uint32_t)f2bf(b.y) << 16);
  o.w = (uint32_t)f2bf(b.z) | ((uint32_t)f2bf(b.w) << 16);
  ((uint4*)dst)[i] = o;
}

// ---------------- transpose f32 [R][C] -> bf16 [C][R] ----------------
__global__ void k_transpose_bf16(const float* __restrict__ src, u16* __restrict__ dst,
                                 int R, int C) {
  __shared__ float tile[32][33];
  int cb = blockIdx.x * 32, rb = blockIdx.y * 32;
  int tx = threadIdx.x, ty = threadIdx.y;
#pragma unroll
  for (int j = 0; j < 4; ++j)
    tile[ty + j * 8][tx] = src[(size_t)(rb + ty + j * 8) * C + cb + tx];
  __syncthreads();
#pragma unroll
  for (int j = 0; j < 4; ++j)
    dst[(size_t)(cb + ty + j * 8) * R + rb + tx] = f2bf(tile[tx][ty + j * 8]);
}

// ---------------- transpose V slice of cqkv -> VT[b*8+kvh][64][2048] (bf16) ----
__global__ void k_transpose_v(const u16* __restrict__ cqkv, u16* __restrict__ vt) {
  __shared__ u16 tile[32][34];
  int st = blockIdx.x, dt = blockIdx.y, bk = blockIdx.z;
  int b = bk >> 3, kvh = bk & 7;
  int tx = threadIdx.x, ty = threadIdx.y;
  const u16* src = cqkv + (size_t)(b * 2048 + st * 32) * 3072 + 2560 + kvh * 64 + dt * 32;
#pragma unroll
  for (int j = 0; j < 4; ++j)
    tile[ty + j * 8][tx] = src[(size_t)(ty + j * 8) * 3072 + tx];
  __syncthreads();
  u16* dst = vt + ((size_t)(bk * 64 + dt * 32)) * 2048 + st * 32;
#pragma unroll
  for (int j = 0; j < 4; ++j)
    dst[(size_t)(ty + j * 8) * 2048 + tx] = tile[tx][ty + j * 8];
}

// ---------------- GEMM: C[M,N] = A[M,K] @ Bt[N,K]^T + bias ----------------
template <bool BF16OUT>
__global__ __launch_bounds__(256) void k_gemm_bt(
    const u16* __restrict__ A, const u16* __restrict__ Bt,
    const float* __restrict__ bias, void* __restrict__ Cptr,
    int M, int N, int K) {
  __shared__ u16 As[128 * 32];
  __shared__ u16 Bs[128 * 32];
  const int t = threadIdx.x;
  const int lane = t & 63;
  const int w = t >> 6, wr = w >> 1, wc = w & 1;
  const int brow = blockIdx.y * 128, bcol = blockIdx.x * 128;
  const int g = lane >> 4, q = lane & 15;

  f32x4 acc[4][4] = {};
  const int srow = t >> 2;
  const int sj = t & 3;
  const int nkt = K >> 5;
  for (int kt = 0; kt < nkt; ++kt) {
    __syncthreads();
#pragma unroll
    for (int i = 0; i < 2; ++i) {
      int row = srow + i * 64;
      int jsrc = sj ^ ((row >> 1) & 3);
      const u16* ga = A + (size_t)(brow + row) * K + kt * 32 + jsrc * 8;
      const u16* gb = Bt + (size_t)(bcol + row) * K + kt * 32 + jsrc * 8;
      GLOAD_LDS16(ga, (char*)As + i * 4096 + t * 16);
      GLOAD_LDS16(gb, (char*)Bs + i * 4096 + t * 16);
    }
    __syncthreads();
    bf16x8 a[4], b[4];
#pragma unroll
    for (int mt = 0; mt < 4; ++mt) {
      int row = wr * 64 + mt * 16 + q;
      int pos = g ^ ((row >> 1) & 3);
      a[mt] = *(const bf16x8*)(As + row * 32 + pos * 8);
    }
#pragma unroll
    for (int nt = 0; nt < 4; ++nt) {
      int row = wc * 64 + nt * 16 + q;
      int pos = g ^ ((row >> 1) & 3);
      b[nt] = *(const bf16x8*)(Bs + row * 32 + pos * 8);
    }
#pragma unroll
    for (int mt = 0; mt < 4; ++mt)
#pragma unroll
      for (int nt = 0; nt < 4; ++nt)
        acc[mt][nt] = __builtin_amdgcn_mfma_f32_16x16x32_bf16(a[mt], b[nt], acc[mt][nt], 0, 0, 0);
  }
#pragma unroll
  for (int nt = 0; nt < 4; ++nt) {
    int col = bcol + wc * 64 + nt * 16 + q;
    float bv_ = bias[col];
#pragma unroll
    for (int mt = 0; mt < 4; ++mt) {
#pragma unroll
      for (int r = 0; r < 4; ++r) {
        int row = brow + wr * 64 + mt * 16 + g * 4 + r;
        float val = acc[mt][nt][r] + bv_;
        if (BF16OUT)
          ((u16*)Cptr)[(size_t)row * N + col] = f2bf(val);
        else
          ((float*)Cptr)[(size_t)row * N + col] = val;
      }
    }
  }
}

// ---------------- flash attention v4 (VT-staged, double-buffered, 2-phase) ----
// Block = 4 waves, 128 q rows. qkv: [4096][3072] (Q | K | V cols).
// vt: [b*8+kvh][64][2048] pre-transposed V.
#define LOG2E 1.44269504088896340736f
__global__ __launch_bounds__(256) void k_attn(const u16* __restrict__ qkv,
                                              const u16* __restrict__ vt,
                                              u16* __restrict__ out) {
  const int qt = blockIdx.x, h = blockIdx.y, b = blockIdx.z;
  const int kvh = h >> 2;
  const int t = threadIdx.x, lane = t & 63, w = t >> 6;
  const int g = lane >> 4, q16 = lane & 15;
  const int LDQ = 3072;

  __shared__ u16 Ksh[2][64 * 64];   // [kv][d], chunk (row,j) holds dc = j ^ (row&7)
  __shared__ u16 Vsh[2][64 * 64];   // [d][kv], chunk (d,j)  holds kc = j ^ (d&7)
  __shared__ u16 Psh[4][16 * 72] __attribute__((aligned(16)));

  // Q fragments, scaled by 1/8 (exact in bf16)
  bf16x8 qf[2][2];
#pragma unroll
  for (int sub = 0; sub < 2; ++sub) {
    const size_t qrow = (size_t)(b * 2048 + qt * 128 + sub * 64 + w * 16 + q16);
#pragma unroll
    for (int c = 0; c < 2; ++c) {
      bf16x8 tmp = *(const bf16x8*)(qkv + qrow * LDQ + h * 64 + c * 32 + g * 8);
#pragma unroll
      for (int i = 0; i < 8; ++i)
        tmp[i] = (short)f2bf(bf2f((u16)tmp[i]) * 0.125f);
      qf[sub][c] = tmp;
    }
  }

  f32x4 acc[2][4] = {};
  float m_run[2], l_run[2];
  m_run[0] = m_run[1] = -__builtin_inff();
  l_run[0] = l_run[1] = 0.f;

  const int kbase = b * 2048;
  const int koff = 2048 + kvh * 64;
  const u16* vtb = vt + (size_t)((b * 8 + kvh) * 64) * 2048;
  const int srow = t >> 3;  // 0..31
  const int sj = t & 7;

  auto stage = [&](int bb, int kt_) {
#pragma unroll
    for (int p = 0; p < 2; ++p) {
      int row = srow + p * 32;
      int cx = sj ^ (row & 7);
      const u16* gk = qkv + (size_t)(kbase + kt_ * 64 + row) * LDQ + koff + cx * 8;
      GLOAD_LDS16(gk, (char*)Ksh[bb] + p * 4096 + t * 16);
      const u16* gv = vtb + (size_t)row * 2048 + kt_ * 64 + cx * 8;
      GLOAD_LDS16(gv, (char*)Vsh[bb] + p * 4096 + t * 16);
    }
  };

  stage(0, 0);
  __syncthreads();
  int cur = 0;

  for (int kt = 0; kt < 32; ++kt) {
    if (kt < 31) stage(cur ^ 1, kt + 1);   // prefetch next tile (hidden under compute)
    const u16* Kc = Ksh[cur];
    const u16* Vc = Vsh[cur];

    // ---- QK^T swapped: sc = mfma(K, Q) -> row = kv (nt*16+g*4+r), col = q (l&15)
    f32x4 sc[2][4] = {};
    __builtin_amdgcn_s_setprio(1);
#pragma unroll
    for (int c = 0; c < 2; ++c) {
#pragma unroll
      for (int nt = 0; nt < 4; ++nt) {
        int row = nt * 16 + q16;
        bf16x8 kf = *(const bf16x8*)(Kc + row * 64 + (((c * 4 + g) ^ (row & 7)) << 3));
        sc[0][nt] = __builtin_amdgcn_mfma_f32_16x16x32_bf16(kf, qf[0][c], sc[0][nt], 0, 0, 0);
        sc[1][nt] = __builtin_amdgcn_mfma_f32_16x16x32_bf16(kf, qf[1][c], sc[1][nt], 0, 0, 0);
      }
    }
    __builtin_amdgcn_s_setprio(0);

    bf16x8 pf[2][2];
#pragma unroll
    for (int sub = 0; sub < 2; ++sub) {
      // row max: per-lane 16 values all belong to q = l&15; 2-step cross-group reduce
      float mt_ = sc[sub][0][0];
#pragma unroll
      for (int nt = 0; nt < 4; ++nt)
#pragma unroll
        for (int r = 0; r < 4; ++r)
          mt_ = fmaxf(mt_, sc[sub][nt][r]);
      mt_ = fmaxf(mt_, __shfl_xor(mt_, 16, 64));
      mt_ = fmaxf(mt_, __shfl_xor(mt_, 32, 64));
      // defer-rescale: only touch acc when some row saw a new max
      if (__any(mt_ > m_run[sub])) {
        float mn = fmaxf(m_run[sub], mt_);
        float alpha = EXP2F((m_run[sub] - mn) * LOG2E);
        m_run[sub] = mn;
        l_run[sub] *= alpha;
#pragma unroll
        for (int r = 0; r < 4; ++r) {
          float ar = __shfl(alpha, g * 4 + r, 64);
#pragma unroll
          for (int dt = 0; dt < 4; ++dt) acc[sub][dt][r] *= ar;
        }
      }
      float mL = m_run[sub] * LOG2E;
      float lt = 0.f;
#pragma unroll
      for (int nt = 0; nt < 4; ++nt)
#pragma unroll
        for (int r = 0; r < 4; ++r) {
          float p_ = EXP2F(fmaf(sc[sub][nt][r], LOG2E, -mL));
          sc[sub][nt][r] = p_;
          lt += p_;
        }
      lt += __shfl_xor(lt, 16, 64);
      lt += __shfl_xor(lt, 32, 64);
      l_run[sub] += lt;
      // pack P -> LDS (per-wave buffer, same-wave DS in-order; no block barrier)
      u16* prow = &Psh[w][q16 * 72];
#pragma unroll
      for (int nt = 0; nt < 4; ++nt) {
        u32x2 pk;
        pk.x = cvt_pk_bf16(sc[sub][nt][0], sc[sub][nt][1]);
        pk.y = cvt_pk_bf16(sc[sub][nt][2], sc[sub][nt][3]);
        *(u32x2*)(prow + nt * 16 + g * 4) = pk;
      }
      pf[sub][0] = *(const bf16x8*)(&Psh[w][q16 * 72 + g * 8]);
      pf[sub][1] = *(const bf16x8*)(&Psh[w][q16 * 72 + 32 + g * 8]);
    }

    // ---- PV: vf from swizzled Vsh (same read pattern as K) ----
    __builtin_amdgcn_s_setprio(1);
#pragma unroll
    for (int c = 0; c < 2; ++c) {
      int kc = c * 4 + g;
#pragma unroll
      for (int dt = 0; dt < 4; ++dt) {
        int d = dt * 16 + q16;
        bf16x8 vf = *(const bf16x8*)(Vc + d * 64 + ((kc ^ (d & 7)) << 3));
        acc[0][dt] = __builtin_amdgcn_mfma_f32_16x16x32_bf16(pf[0][c], vf, acc[0][dt], 0, 0, 0);
        acc[1][dt] = __builtin_amdgcn_mfma_f32_16x16x32_bf16(pf[1][c], vf, acc[1][dt], 0, 0, 0);
      }
    }
    __builtin_amdgcn_s_setprio(0);

    __syncthreads();   // drains vmcnt (prefetch landed) + syncs buffer swap
    cur ^= 1;
  }

  // ---- epilogue: rows g*4+r, cols dt*16+q16 ----
#pragma unroll
  for (int sub = 0; sub < 2; ++sub)
#pragma unroll
    for (int r = 0; r < 4; ++r) {
      float linv = 1.0f / __shfl(l_run[sub], g * 4 + r, 64);
      size_t orow = (size_t)(b * 2048 + qt * 128 + sub * 64 + w * 16 + g * 4 + r);
#pragma unroll
      for (int dt = 0; dt < 4; ++dt)
        out[orow * 2048 + h * 64 + dt * 16 + q16] = f2bf(acc[sub][dt][r] * linv);
    }
}

// ---------------- launch ----------------
extern "C" void kernel_launch(void* const* d_in, const int* in_sizes, int n_in,
                              void* d_out, int out_size, void* d_ws, size_t ws_size,
                              hipStream_t stream) {
  const float* x  = (const float*)d_in[0];
  const float* Wq = (const float*)d_in[1];
  const float* bq = (const float*)d_in[2];
  const float* Wk = (const float*)d_in[3];
  const float* bk = (const float*)d_in[4];
  const float* Wv = (const float*)d_in[5];
  const float* bv = (const float*)d_in[6];
  const float* Wo = (const float*)d_in[7];
  const float* bo = (const float*)d_in[8];
  float* out = (float*)d_out;

  char* ws = (char*)d_ws;
  u16*   xb    = (u16*)(ws + 0);               // 4096x2048 bf16 = 16 MB; reused as VT after QKV GEMM
  u16*   wqkvT = (u16*)(ws + 16777216);        // 3072x2048 bf16 = 12 MB
  u16*   woT   = (u16*)(ws + 29360128);        // 2048x2048 bf16 = 8 MB
  float* bqkv  = (float*)(ws + 37748736);      // 3072 f32
  u16*   cqkv  = (u16*)(ws + 37761024);        // 4096x3072 bf16 = 24 MB
  u16*   aout  = (u16*)(ws + 62926848);        // 4096x2048 bf16 = 16 MB
  u16*   vtb   = xb;                           // VT: 16x64x2048 bf16 = 4 MB (xb is dead post-GEMM)
  (void)ws_size; (void)in_sizes; (void)n_in; (void)out_size;

  hipMemcpyAsync(bqkv, bq, 2048 * sizeof(float), hipMemcpyDeviceToDevice, stream);
  hipMemcpyAsync(bqkv + 2048, bk, 512 * sizeof(float), hipMemcpyDeviceToDevice, stream);
  hipMemcpyAsync(bqkv + 2560, bv, 512 * sizeof(float), hipMemcpyDeviceToDevice, stream);

  k_conv_bf16<<<4096, 256, 0, stream>>>(x, xb, 1048576);
  dim3 tb(32, 8);
  k_transpose_bf16<<<dim3(64, 64), tb, 0, stream>>>(Wq, wqkvT, 2048, 2048);
  k_transpose_bf16<<<dim3(16, 64), tb, 0, stream>>>(Wk, wqkvT + 2048 * 2048, 2048, 512);
  k_transpose_bf16<<<dim3(16, 64), tb, 0, stream>>>(Wv, wqkvT + 2560 * 2048, 2048, 512);
  k_transpose_bf16<<<dim3(64, 64), tb, 0, stream>>>(Wo, woT, 2048, 2048);

  k_gemm_bt<true><<<dim3(24, 32), 256, 0, stream>>>(xb, wqkvT, bqkv, cqkv, 4096, 3072, 2048);
  k_transpose_v<<<dim3(64, 2, 16), tb, 0, stream>>>(cqkv, vtb);
  k_attn<<<dim3(16, 32, 2), 256, 0, stream>>>(cqkv, vtb, aout);
  k_gemm_bt<false><<<dim3(16, 32), 256, 0, stream>>>(aout, woT, bo, out, 4096, 2048, 2048);
}

// Round 7
// 380.291 us; speedup vs baseline: 1.3425x; 1.0464x over previous
//
#include <hip/hip_runtime.h>
#include <stdint.h>

typedef unsigned short u16;
typedef unsigned int u32;
typedef short bf16x8 __attribute__((ext_vector_type(8)));
typedef float f32x4 __attribute__((ext_vector_type(4)));
typedef u32 u32x2 __attribute__((ext_vector_type(2)));

#define GLOAD_LDS16(gptr, lptr)                                                \
  __builtin_amdgcn_global_load_lds(                                            \
      (__attribute__((address_space(1))) void*)(gptr),                         \
      (__attribute__((address_space(3))) void*)(lptr), 16, 0, 0)

#if __has_builtin(__builtin_amdgcn_exp2f)
#define EXP2F(x) __builtin_amdgcn_exp2f(x)
#else
#define EXP2F(x) exp2f(x)
#endif

__device__ __forceinline__ u16 f2bf(float f) {
  union { float f; uint32_t u; } v; v.f = f;
  return (u16)((v.u + 0x7fffu + ((v.u >> 16) & 1u)) >> 16);
}
__device__ __forceinline__ float bf2f(u16 h) {
  union { uint32_t u; float f; } v; v.u = ((uint32_t)h) << 16;
  return v.f;
}
__device__ __forceinline__ u32 cvt_pk_bf16(float lo, float hi) {
  u32 r;
  asm("v_cvt_pk_bf16_f32 %0, %1, %2" : "=v"(r) : "v"(lo), "v"(hi));
  return r;
}

// ---------------- convert x (f32 -> bf16), 8 elems/thread ----------------
__global__ void k_conv_bf16(const float* __restrict__ src, u16* __restrict__ dst, int n8) {
  int i = blockIdx.x * blockDim.x + threadIdx.x;
  if (i >= n8) return;
  const float4* s = (const float4*)src + (size_t)i * 2;
  float4 a = s[0], b = s[1];
  uint4 o;
  o.x = (uint32_t)f2bf(a.x) | ((uint32_t)f2bf(a.y) << 16);
  o.y = (uint32_t)f2bf(a.z) | ((uint32_t)f2bf(a.w) << 16);
  o.z = (uint32_t)f2bf(b.x) | ((uint32_t)f2bf(b.y) << 16);
  o.w = (uint32_t)f2bf(b.z) | ((uint32_t)f2bf(b.w) << 16);
  ((uint4*)dst)[i] = o;
}

// ---------------- transpose f32 [R][C] -> bf16 [C][R] ----------------
__global__ void k_transpose_bf16(const float* __restrict__ src, u16* __restrict__ dst,
                                 int R, int C) {
  __shared__ float tile[32][33];
  int cb = blockIdx.x * 32, rb = blockIdx.y * 32;
  int tx = threadIdx.x, ty = threadIdx.y;
#pragma unroll
  for (int j = 0; j < 4; ++j)
    tile[ty + j * 8][tx] = src[(size_t)(rb + ty + j * 8) * C + cb + tx];
  __syncthreads();
#pragma unroll
  for (int j = 0; j < 4; ++j)
    dst[(size_t)(cb + ty + j * 8) * R + rb + tx] = f2bf(tile[tx][ty + j * 8]);
}

// ---------------- transpose V slice of cqkv -> VT[b*8+kvh][64][2048] (bf16) ----
__global__ void k_transpose_v(const u16* __restrict__ cqkv, u16* __restrict__ vt) {
  __shared__ u16 tile[32][34];
  int st = blockIdx.x, dt = blockIdx.y, bk = blockIdx.z;
  int b = bk >> 3, kvh = bk & 7;
  int tx = threadIdx.x, ty = threadIdx.y;
  const u16* src = cqkv + (size_t)(b * 2048 + st * 32) * 3072 + 2560 + kvh * 64 + dt * 32;
#pragma unroll
  for (int j = 0; j < 4; ++j)
    tile[ty + j * 8][tx] = src[(size_t)(ty + j * 8) * 3072 + tx];
  __syncthreads();
  u16* dst = vt + ((size_t)(bk * 64 + dt * 32)) * 2048 + st * 32;
#pragma unroll
  for (int j = 0; j < 4; ++j)
    dst[(size_t)(ty + j * 8) * 2048 + tx] = tile[tx][ty + j * 8];
}

// ---------------- GEMM v2: 2-phase double-buffered, XCD-swizzled ----------------
// C[M,N] = A[M,K] @ Bt[N,K]^T + bias. 128x128 tile, BK=32, 4 waves.
template <bool BF16OUT>
__global__ __launch_bounds__(256) void k_gemm_bt(
    const u16* __restrict__ A, const u16* __restrict__ Bt,
    const float* __restrict__ bias, void* __restrict__ Cptr,
    int M, int N, int K, int gx, int nwg) {
  __shared__ u16 As[2][128 * 32];
  __shared__ u16 Bs[2][128 * 32];
  const int t = threadIdx.x;
  const int lane = t & 63;
  const int w = t >> 6, wr = w >> 1, wc = w & 1;
  // bijective XCD-chunked swizzle (nwg % 8 == 0)
  const int bid = blockIdx.x;
  const int cpx = nwg >> 3;
  const int swz = (bid & 7) * cpx + (bid >> 3);
  const int brow = (swz / gx) * 128, bcol = (swz % gx) * 128;
  const int g = lane >> 4, q = lane & 15;

  f32x4 acc[4][4] = {};
  const int srow = t >> 2;
  const int sj = t & 3;
  const int nkt = K >> 5;

  auto stage = [&](int bb, int kt_) {
#pragma unroll
    for (int i = 0; i < 2; ++i) {
      int row = srow + i * 64;
      int jsrc = sj ^ ((row >> 1) & 3);
      const u16* ga = A + (size_t)(brow + row) * K + kt_ * 32 + jsrc * 8;
      const u16* gb = Bt + (size_t)(bcol + row) * K + kt_ * 32 + jsrc * 8;
      GLOAD_LDS16(ga, (char*)(&As[bb][0]) + i * 4096 + t * 16);
      GLOAD_LDS16(gb, (char*)(&Bs[bb][0]) + i * 4096 + t * 16);
    }
  };

  stage(0, 0);
  __syncthreads();
  int cur = 0;

  for (int kt = 0; kt < nkt; ++kt) {
    if (kt < nkt - 1) stage(cur ^ 1, kt + 1);  // prefetch next K-step
    const u16* Ac = As[cur];
    const u16* Bc = Bs[cur];
    bf16x8 a[4], b[4];
#pragma unroll
    for (int mt = 0; mt < 4; ++mt) {
      int row = wr * 64 + mt * 16 + q;
      int pos = g ^ ((row >> 1) & 3);
      a[mt] = *(const bf16x8*)(Ac + row * 32 + pos * 8);
    }
#pragma unroll
    for (int nt = 0; nt < 4; ++nt) {
      int row = wc * 64 + nt * 16 + q;
      int pos = g ^ ((row >> 1) & 3);
      b[nt] = *(const bf16x8*)(Bc + row * 32 + pos * 8);
    }
    __builtin_amdgcn_s_setprio(1);
#pragma unroll
    for (int mt = 0; mt < 4; ++mt)
#pragma unroll
      for (int nt = 0; nt < 4; ++nt)
        acc[mt][nt] = __builtin_amdgcn_mfma_f32_16x16x32_bf16(a[mt], b[nt], acc[mt][nt], 0, 0, 0);
    __builtin_amdgcn_s_setprio(0);
    __syncthreads();  // drains prefetch vmcnt + swaps buffers
    cur ^= 1;
  }
#pragma unroll
  for (int nt = 0; nt < 4; ++nt) {
    int col = bcol + wc * 64 + nt * 16 + q;
    float bv_ = bias[col];
#pragma unroll
    for (int mt = 0; mt < 4; ++mt) {
#pragma unroll
      for (int r = 0; r < 4; ++r) {
        int row = brow + wr * 64 + mt * 16 + g * 4 + r;
        float val = acc[mt][nt][r] + bv_;
        if (BF16OUT)
          ((u16*)Cptr)[(size_t)row * N + col] = f2bf(val);
        else
          ((float*)Cptr)[(size_t)row * N + col] = val;
      }
    }
  }
}

// ---------------- flash attention v4 (VT-staged, double-buffered, 2-phase) ----
// EXACT round-4 passing version (Psh stride-72, shfl-based l). Bisect control.
#define LOG2E 1.44269504088896340736f
__global__ __launch_bounds__(256) void k_attn(const u16* __restrict__ qkv,
                                              const u16* __restrict__ vt,
                                              u16* __restrict__ out) {
  const int qt = blockIdx.x, h = blockIdx.y, b = blockIdx.z;
  const int kvh = h >> 2;
  const int t = threadIdx.x, lane = t & 63, w = t >> 6;
  const int g = lane >> 4, q16 = lane & 15;
  const int LDQ = 3072;

  __shared__ u16 Ksh[2][64 * 64];   // [kv][d], chunk (row,j) holds dc = j ^ (row&7)
  __shared__ u16 Vsh[2][64 * 64];   // [d][kv], chunk (d,j)  holds kc = j ^ (d&7)
  __shared__ u16 Psh[4][16 * 72] __attribute__((aligned(16)));

  // Q fragments, scaled by 1/8 (exact in bf16)
  bf16x8 qf[2][2];
#pragma unroll
  for (int sub = 0; sub < 2; ++sub) {
    const size_t qrow = (size_t)(b * 2048 + qt * 128 + sub * 64 + w * 16 + q16);
#pragma unroll
    for (int c = 0; c < 2; ++c) {
      bf16x8 tmp = *(const bf16x8*)(qkv + qrow * LDQ + h * 64 + c * 32 + g * 8);
#pragma unroll
      for (int i = 0; i < 8; ++i)
        tmp[i] = (short)f2bf(bf2f((u16)tmp[i]) * 0.125f);
      qf[sub][c] = tmp;
    }
  }

  f32x4 acc[2][4] = {};
  float m_run[2], l_run[2];
  m_run[0] = m_run[1] = -__builtin_inff();
  l_run[0] = l_run[1] = 0.f;

  const int kbase = b * 2048;
  const int koff = 2048 + kvh * 64;
  const u16* vtb = vt + (size_t)((b * 8 + kvh) * 64) * 2048;
  const int srow = t >> 3;  // 0..31
  const int sj = t & 7;

  auto stage = [&](int bb, int kt_) {
#pragma unroll
    for (int p = 0; p < 2; ++p) {
      int row = srow + p * 32;
      int cx = sj ^ (row & 7);
      const u16* gk = qkv + (size_t)(kbase + kt_ * 64 + row) * LDQ + koff + cx * 8;
      GLOAD_LDS16(gk, (char*)(&Ksh[bb][0]) + p * 4096 + t * 16);
      const u16* gv = vtb + (size_t)row * 2048 + kt_ * 64 + cx * 8;
      GLOAD_LDS16(gv, (char*)(&Vsh[bb][0]) + p * 4096 + t * 16);
    }
  };

  stage(0, 0);
  __syncthreads();
  int cur = 0;

  for (int kt = 0; kt < 32; ++kt) {
    if (kt < 31) stage(cur ^ 1, kt + 1);   // prefetch next tile (hidden under compute)
    const u16* Kc = Ksh[cur];
    const u16* Vc = Vsh[cur];

    // ---- QK^T swapped: sc = mfma(K, Q) -> row = kv (nt*16+g*4+r), col = q (l&15)
    f32x4 sc[2][4] = {};
    __builtin_amdgcn_s_setprio(1);
#pragma unroll
    for (int c = 0; c < 2; ++c) {
#pragma unroll
      for (int nt = 0; nt < 4; ++nt) {
        int row = nt * 16 + q16;
        bf16x8 kf = *(const bf16x8*)(Kc + row * 64 + (((c * 4 + g) ^ (row & 7)) << 3));
        sc[0][nt] = __builtin_amdgcn_mfma_f32_16x16x32_bf16(kf, qf[0][c], sc[0][nt], 0, 0, 0);
        sc[1][nt] = __builtin_amdgcn_mfma_f32_16x16x32_bf16(kf, qf[1][c], sc[1][nt], 0, 0, 0);
      }
    }
    __builtin_amdgcn_s_setprio(0);

    bf16x8 pf[2][2];
#pragma unroll
    for (int sub = 0; sub < 2; ++sub) {
      // row max: per-lane 16 values all belong to q = l&15; 2-step cross-group reduce
      float mt_ = sc[sub][0][0];
#pragma unroll
      for (int nt = 0; nt < 4; ++nt)
#pragma unroll
        for (int r = 0; r < 4; ++r)
          mt_ = fmaxf(mt_, sc[sub][nt][r]);
      mt_ = fmaxf(mt_, __shfl_xor(mt_, 16, 64));
      mt_ = fmaxf(mt_, __shfl_xor(mt_, 32, 64));
      // defer-rescale: only touch acc when some row saw a new max
      if (__any(mt_ > m_run[sub])) {
        float mn = fmaxf(m_run[sub], mt_);
        float alpha = EXP2F((m_run[sub] - mn) * LOG2E);
        m_run[sub] = mn;
        l_run[sub] *= alpha;
#pragma unroll
        for (int r = 0; r < 4; ++r) {
          float ar = __shfl(alpha, g * 4 + r, 64);
#pragma unroll
          for (int dt = 0; dt < 4; ++dt) acc[sub][dt][r] *= ar;
        }
      }
      float mL = m_run[sub] * LOG2E;
      float lt = 0.f;
#pragma unroll
      for (int nt = 0; nt < 4; ++nt)
#pragma unroll
        for (int r = 0; r < 4; ++r) {
          float p_ = EXP2F(fmaf(sc[sub][nt][r], LOG2E, -mL));
          sc[sub][nt][r] = p_;
          lt += p_;
        }
      lt += __shfl_xor(lt, 16, 64);
      lt += __shfl_xor(lt, 32, 64);
      l_run[sub] += lt;
      // pack P -> LDS (per-wave buffer, same-wave DS in-order; no block barrier)
      u16* prow = &Psh[w][q16 * 72];
#pragma unroll
      for (int nt = 0; nt < 4; ++nt) {
        u32x2 pk;
        pk.x = cvt_pk_bf16(sc[sub][nt][0], sc[sub][nt][1]);
        pk.y = cvt_pk_bf16(sc[sub][nt][2], sc[sub][nt][3]);
        *(u32x2*)(prow + nt * 16 + g * 4) = pk;
      }
      pf[sub][0] = *(const bf16x8*)(&Psh[w][q16 * 72 + g * 8]);
      pf[sub][1] = *(const bf16x8*)(&Psh[w][q16 * 72 + 32 + g * 8]);
    }

    // ---- PV: vf from swizzled Vsh (same read pattern as K) ----
    __builtin_amdgcn_s_setprio(1);
#pragma unroll
    for (int c = 0; c < 2; ++c) {
      int kc = c * 4 + g;
#pragma unroll
      for (int dt = 0; dt < 4; ++dt) {
        int d = dt * 16 + q16;
        bf16x8 vf = *(const bf16x8*)(Vc + d * 64 + ((kc ^ (d & 7)) << 3));
        acc[0][dt] = __builtin_amdgcn_mfma_f32_16x16x32_bf16(pf[0][c], vf, acc[0][dt], 0, 0, 0);
        acc[1][dt] = __builtin_amdgcn_mfma_f32_16x16x32_bf16(pf[1][c], vf, acc[1][dt], 0, 0, 0);
      }
    }
    __builtin_amdgcn_s_setprio(0);

    __syncthreads();   // drains vmcnt (prefetch landed) + syncs buffer swap
    cur ^= 1;
  }

  // ---- epilogue: rows g*4+r, cols dt*16+q16 ----
#pragma unroll
  for (int sub = 0; sub < 2; ++sub)
#pragma unroll
    for (int r = 0; r < 4; ++r) {
      float linv = 1.0f / __shfl(l_run[sub], g * 4 + r, 64);
      size_t orow = (size_t)(b * 2048 + qt * 128 + sub * 64 + w * 16 + g * 4 + r);
#pragma unroll
      for (int dt = 0; dt < 4; ++dt)
        out[orow * 2048 + h * 64 + dt * 16 + q16] = f2bf(acc[sub][dt][r] * linv);
    }
}

// ---------------- launch ----------------
extern "C" void kernel_launch(void* const* d_in, const int* in_sizes, int n_in,
                              void* d_out, int out_size, void* d_ws, size_t ws_size,
                              hipStream_t stream) {
  const float* x  = (const float*)d_in[0];
  const float* Wq = (const float*)d_in[1];
  const float* bq = (const float*)d_in[2];
  const float* Wk = (const float*)d_in[3];
  const float* bk = (const float*)d_in[4];
  const float* Wv = (const float*)d_in[5];
  const float* bv = (const float*)d_in[6];
  const float* Wo = (const float*)d_in[7];
  const float* bo = (const float*)d_in[8];
  float* out = (float*)d_out;

  char* ws = (char*)d_ws;
  u16*   xb    = (u16*)(ws + 0);               // 4096x2048 bf16 = 16 MB; reused as VT after QKV GEMM
  u16*   wqkvT = (u16*)(ws + 16777216);        // 3072x2048 bf16 = 12 MB
  u16*   woT   = (u16*)(ws + 29360128);        // 2048x2048 bf16 = 8 MB
  float* bqkv  = (float*)(ws + 37748736);      // 3072 f32
  u16*   cqkv  = (u16*)(ws + 37761024);        // 4096x3072 bf16 = 24 MB
  u16*   aout  = (u16*)(ws + 62926848);        // 4096x2048 bf16 = 16 MB
  u16*   vtb   = xb;                           // VT: 16x64x2048 bf16 = 4 MB (xb dead post-GEMM)
  (void)ws_size; (void)in_sizes; (void)n_in; (void)out_size;

  hipMemcpyAsync(bqkv, bq, 2048 * sizeof(float), hipMemcpyDeviceToDevice, stream);
  hipMemcpyAsync(bqkv + 2048, bk, 512 * sizeof(float), hipMemcpyDeviceToDevice, stream);
  hipMemcpyAsync(bqkv + 2560, bv, 512 * sizeof(float), hipMemcpyDeviceToDevice, stream);

  k_conv_bf16<<<4096, 256, 0, stream>>>(x, xb, 1048576);
  dim3 tb(32, 8);
  k_transpose_bf16<<<dim3(64, 64), tb, 0, stream>>>(Wq, wqkvT, 2048, 2048);
  k_transpose_bf16<<<dim3(16, 64), tb, 0, stream>>>(Wk, wqkvT + 2048 * 2048, 2048, 512);
  k_transpose_bf16<<<dim3(16, 64), tb, 0, stream>>>(Wv, wqkvT + 2560 * 2048, 2048, 512);
  k_transpose_bf16<<<dim3(64, 64), tb, 0, stream>>>(Wo, woT, 2048, 2048);

  k_gemm_bt<true><<<768, 256, 0, stream>>>(xb, wqkvT, bqkv, cqkv, 4096, 3072, 2048, 24, 768);
  k_transpose_v<<<dim3(64, 2, 16), tb, 0, stream>>>(cqkv, vtb);
  k_attn<<<dim3(16, 32, 2), 256, 0, stream>>>(cqkv, vtb, aout);
  k_gemm_bt<false><<<512, 256, 0, stream>>>(aout, woT, bo, out, 4096, 2048, 2048, 16, 512);
}

// Round 8
// 372.476 us; speedup vs baseline: 1.3706x; 1.0210x over previous
//
#include <hip/hip_runtime.h>
#include <stdint.h>

typedef unsigned short u16;
typedef unsigned int u32;
typedef short bf16x8 __attribute__((ext_vector_type(8)));
typedef float f32x4 __attribute__((ext_vector_type(4)));
typedef u32 u32x2 __attribute__((ext_vector_type(2)));

#define GLOAD_LDS16(gptr, lptr)                                                \
  __builtin_amdgcn_global_load_lds(                                            \
      (__attribute__((address_space(1))) void*)(gptr),                         \
      (__attribute__((address_space(3))) void*)(lptr), 16, 0, 0)

#if __has_builtin(__builtin_amdgcn_exp2f)
#define EXP2F(x) __builtin_amdgcn_exp2f(x)
#else
#define EXP2F(x) exp2f(x)
#endif

__device__ __forceinline__ u16 f2bf(float f) {
  union { float f; uint32_t u; } v; v.f = f;
  return (u16)((v.u + 0x7fffu + ((v.u >> 16) & 1u)) >> 16);
}
__device__ __forceinline__ float bf2f(u16 h) {
  union { uint32_t u; float f; } v; v.u = ((uint32_t)h) << 16;
  return v.f;
}
__device__ __forceinline__ u32 cvt_pk_bf16(float lo, float hi) {
  u32 r;
  asm("v_cvt_pk_bf16_f32 %0, %1, %2" : "=v"(r) : "v"(lo), "v"(hi));
  return r;
}

// ---------------- convert x (f32 -> bf16), 8 elems/thread ----------------
__global__ void k_conv_bf16(const float* __restrict__ src, u16* __restrict__ dst, int n8) {
  int i = blockIdx.x * blockDim.x + threadIdx.x;
  if (i >= n8) return;
  const float4* s = (const float4*)src + (size_t)i * 2;
  float4 a = s[0], b = s[1];
  uint4 o;
  o.x = (uint32_t)f2bf(a.x) | ((uint32_t)f2bf(a.y) << 16);
  o.y = (uint32_t)f2bf(a.z) | ((uint32_t)f2bf(a.w) << 16);
  o.z = (uint32_t)f2bf(b.x) | ((uint32_t)f2bf(b.y) << 16);
  o.w = (uint32_t)f2bf(b.z) | ((uint32_t)f2bf(b.w) << 16);
  ((uint4*)dst)[i] = o;
}

// ---------------- transpose f32 [R][C] -> bf16 [C][R] ----------------
__global__ void k_transpose_bf16(const float* __restrict__ src, u16* __restrict__ dst,
                                 int R, int C) {
  __shared__ float tile[32][33];
  int cb = blockIdx.x * 32, rb = blockIdx.y * 32;
  int tx = threadIdx.x, ty = threadIdx.y;
#pragma unroll
  for (int j = 0; j < 4; ++j)
    tile[ty + j * 8][tx] = src[(size_t)(rb + ty + j * 8) * C + cb + tx];
  __syncthreads();
#pragma unroll
  for (int j = 0; j < 4; ++j)
    dst[(size_t)(cb + ty + j * 8) * R + rb + tx] = f2bf(tile[tx][ty + j * 8]);
}

// ---------------- transpose V slice of cqkv -> VT[b*8+kvh][64][2048] (bf16) ----
__global__ void k_transpose_v(const u16* __restrict__ cqkv, u16* __restrict__ vt) {
  __shared__ u16 tile[32][34];
  int st = blockIdx.x, dt = blockIdx.y, bk = blockIdx.z;
  int b = bk >> 3, kvh = bk & 7;
  int tx = threadIdx.x, ty = threadIdx.y;
  const u16* src = cqkv + (size_t)(b * 2048 + st * 32) * 3072 + 2560 + kvh * 64 + dt * 32;
#pragma unroll
  for (int j = 0; j < 4; ++j)
    tile[ty + j * 8][tx] = src[(size_t)(ty + j * 8) * 3072 + tx];
  __syncthreads();
  u16* dst = vt + ((size_t)(bk * 64 + dt * 32)) * 2048 + st * 32;
#pragma unroll
  for (int j = 0; j < 4; ++j)
    dst[(size_t)(ty + j * 8) * 2048 + tx] = tile[tx][ty + j * 8];
}

// ---------------- GEMM v2: 2-phase double-buffered, XCD-swizzled ----------------
// C[M,N] = A[M,K] @ Bt[N,K]^T + bias. 128x128 tile, BK=32, 4 waves. (r7-proven)
template <bool BF16OUT>
__global__ __launch_bounds__(256) void k_gemm_bt(
    const u16* __restrict__ A, const u16* __restrict__ Bt,
    const float* __restrict__ bias, void* __restrict__ Cptr,
    int M, int N, int K, int gx, int nwg) {
  __shared__ u16 As[2][128 * 32];
  __shared__ u16 Bs[2][128 * 32];
  const int t = threadIdx.x;
  const int lane = t & 63;
  const int w = t >> 6, wr = w >> 1, wc = w & 1;
  const int bid = blockIdx.x;
  const int cpx = nwg >> 3;
  const int swz = (bid & 7) * cpx + (bid >> 3);
  const int brow = (swz / gx) * 128, bcol = (swz % gx) * 128;
  const int g = lane >> 4, q = lane & 15;

  f32x4 acc[4][4] = {};
  const int srow = t >> 2;
  const int sj = t & 3;
  const int nkt = K >> 5;

  auto stage = [&](int bb, int kt_) {
#pragma unroll
    for (int i = 0; i < 2; ++i) {
      int row = srow + i * 64;
      int jsrc = sj ^ ((row >> 1) & 3);
      const u16* ga = A + (size_t)(brow + row) * K + kt_ * 32 + jsrc * 8;
      const u16* gb = Bt + (size_t)(bcol + row) * K + kt_ * 32 + jsrc * 8;
      GLOAD_LDS16(ga, (char*)(&As[bb][0]) + i * 4096 + t * 16);
      GLOAD_LDS16(gb, (char*)(&Bs[bb][0]) + i * 4096 + t * 16);
    }
  };

  stage(0, 0);
  __syncthreads();
  int cur = 0;

  for (int kt = 0; kt < nkt; ++kt) {
    if (kt < nkt - 1) stage(cur ^ 1, kt + 1);
    const u16* Ac = As[cur];
    const u16* Bc = Bs[cur];
    bf16x8 a[4], b[4];
#pragma unroll
    for (int mt = 0; mt < 4; ++mt) {
      int row = wr * 64 + mt * 16 + q;
      int pos = g ^ ((row >> 1) & 3);
      a[mt] = *(const bf16x8*)(Ac + row * 32 + pos * 8);
    }
#pragma unroll
    for (int nt = 0; nt < 4; ++nt) {
      int row = wc * 64 + nt * 16 + q;
      int pos = g ^ ((row >> 1) & 3);
      b[nt] = *(const bf16x8*)(Bc + row * 32 + pos * 8);
    }
    __builtin_amdgcn_s_setprio(1);
#pragma unroll
    for (int mt = 0; mt < 4; ++mt)
#pragma unroll
      for (int nt = 0; nt < 4; ++nt)
        acc[mt][nt] = __builtin_amdgcn_mfma_f32_16x16x32_bf16(a[mt], b[nt], acc[mt][nt], 0, 0, 0);
    __builtin_amdgcn_s_setprio(0);
    __syncthreads();
    cur ^= 1;
  }
#pragma unroll
  for (int nt = 0; nt < 4; ++nt) {
    int col = bcol + wc * 64 + nt * 16 + q;
    float bv_ = bias[col];
#pragma unroll
    for (int mt = 0; mt < 4; ++mt) {
#pragma unroll
      for (int r = 0; r < 4; ++r) {
        int row = brow + wr * 64 + mt * 16 + g * 4 + r;
        float val = acc[mt][nt][r] + bv_;
        if (BF16OUT)
          ((u16*)Cptr)[(size_t)row * N + col] = f2bf(val);
        else
          ((float*)Cptr)[(size_t)row * N + col] = val;
      }
    }
  }
}

// ---------------- flash attention v7: 4 q-subtiles (256 q-rows/block) ----------
// Block = 4 waves. Wave w, sub s -> q rows qt*256 + s*64 + w*16 + 0..15.
// Subs processed in 2 pairs to bound register lifetime; staging/barrier
// amortized 4x vs r4. Inner per-pair code identical to r7 (verified).
#define LOG2E 1.44269504088896340736f
__global__ __launch_bounds__(256) void k_attn(const u16* __restrict__ qkv,
                                              const u16* __restrict__ vt,
                                              u16* __restrict__ out) {
  const int qt = blockIdx.x, h = blockIdx.y, b = blockIdx.z;
  const int kvh = h >> 2;
  const int t = threadIdx.x, lane = t & 63, w = t >> 6;
  const int g = lane >> 4, q16 = lane & 15;
  const int LDQ = 3072;

  __shared__ u16 Ksh[2][64 * 64];   // [kv][d], chunk (row,j) holds dc = j ^ (row&7)
  __shared__ u16 Vsh[2][64 * 64];   // [d][kv], chunk (d,j)  holds kc = j ^ (d&7)
  __shared__ u16 Psh[4][16 * 72] __attribute__((aligned(16)));

  // Q fragments, scaled by 1/8 (exact in bf16)
  bf16x8 qf[4][2];
#pragma unroll
  for (int s = 0; s < 4; ++s) {
    const size_t qrow = (size_t)(b * 2048 + qt * 256 + s * 64 + w * 16 + q16);
#pragma unroll
    for (int c = 0; c < 2; ++c) {
      bf16x8 tmp = *(const bf16x8*)(qkv + qrow * LDQ + h * 64 + c * 32 + g * 8);
#pragma unroll
      for (int i = 0; i < 8; ++i)
        tmp[i] = (short)f2bf(bf2f((u16)tmp[i]) * 0.125f);
      qf[s][c] = tmp;
    }
  }

  f32x4 acc[4][4] = {};
  float m_run[4], l_run[4];
#pragma unroll
  for (int s = 0; s < 4; ++s) { m_run[s] = -__builtin_inff(); l_run[s] = 0.f; }

  const int kbase = b * 2048;
  const int koff = 2048 + kvh * 64;
  const u16* vtb = vt + (size_t)((b * 8 + kvh) * 64) * 2048;
  const int srow = t >> 3;  // 0..31
  const int sj = t & 7;
  const int cx = sj ^ (srow & 7);  // (srow + p*32)&7 == srow&7, shared for both halves

  // hoisted incremental staging pointers (advance per tile)
  const u16* gk = qkv + (size_t)(kbase + srow) * LDQ + koff + cx * 8;
  const u16* gv = vtb + (size_t)srow * 2048 + cx * 8;

  auto stage = [&](int bb) {
    GLOAD_LDS16(gk,               (char*)(&Ksh[bb][0]) + t * 16);
    GLOAD_LDS16(gk + 32 * LDQ,    (char*)(&Ksh[bb][0]) + 4096 + t * 16);
    GLOAD_LDS16(gv,               (char*)(&Vsh[bb][0]) + t * 16);
    GLOAD_LDS16(gv + 32 * 2048,   (char*)(&Vsh[bb][0]) + 4096 + t * 16);
  };

  stage(0);
  gk += 64 * LDQ; gv += 64;
  __syncthreads();
  int cur = 0;

  for (int kt = 0; kt < 32; ++kt) {
    if (kt < 31) { stage(cur ^ 1); gk += 64 * LDQ; gv += 64; }
    const u16* Kc = Ksh[cur];
    const u16* Vc = Vsh[cur];

#pragma unroll
    for (int p2 = 0; p2 < 2; ++p2) {
      const int s0 = p2 * 2, s1 = p2 * 2 + 1;
      // ---- QK^T swapped: sc = mfma(K, Q) -> row = kv (nt*16+g*4+r), col = q16
      f32x4 sc[2][4] = {};
      __builtin_amdgcn_s_setprio(1);
#pragma unroll
      for (int c = 0; c < 2; ++c) {
#pragma unroll
        for (int nt = 0; nt < 4; ++nt) {
          int row = nt * 16 + q16;
          bf16x8 kf = *(const bf16x8*)(Kc + row * 64 + (((c * 4 + g) ^ (row & 7)) << 3));
          sc[0][nt] = __builtin_amdgcn_mfma_f32_16x16x32_bf16(kf, qf[s0][c], sc[0][nt], 0, 0, 0);
          sc[1][nt] = __builtin_amdgcn_mfma_f32_16x16x32_bf16(kf, qf[s1][c], sc[1][nt], 0, 0, 0);
        }
      }
      __builtin_amdgcn_s_setprio(0);

      bf16x8 pf[2][2];
#pragma unroll
      for (int i2 = 0; i2 < 2; ++i2) {
        const int s = p2 * 2 + i2;
        // row max: per-lane 16 values belong to q = l&15; 2-step cross-group reduce
        float mt_ = sc[i2][0][0];
#pragma unroll
        for (int nt = 0; nt < 4; ++nt)
#pragma unroll
          for (int r = 0; r < 4; ++r)
            mt_ = fmaxf(mt_, sc[i2][nt][r]);
        mt_ = fmaxf(mt_, __shfl_xor(mt_, 16, 64));
        mt_ = fmaxf(mt_, __shfl_xor(mt_, 32, 64));
        if (__any(mt_ > m_run[s])) {
          float mn = fmaxf(m_run[s], mt_);
          float alpha = EXP2F((m_run[s] - mn) * LOG2E);
          m_run[s] = mn;
          l_run[s] *= alpha;
#pragma unroll
          for (int r = 0; r < 4; ++r) {
            float ar = __shfl(alpha, g * 4 + r, 64);
#pragma unroll
            for (int dt = 0; dt < 4; ++dt) acc[s][dt][r] *= ar;
          }
        }
        float mL = m_run[s] * LOG2E;
        float lt = 0.f;
#pragma unroll
        for (int nt = 0; nt < 4; ++nt)
#pragma unroll
          for (int r = 0; r < 4; ++r) {
            float p_ = EXP2F(fmaf(sc[i2][nt][r], LOG2E, -mL));
            sc[i2][nt][r] = p_;
            lt += p_;
          }
        lt += __shfl_xor(lt, 16, 64);
        lt += __shfl_xor(lt, 32, 64);
        l_run[s] += lt;
        // pack P -> per-wave LDS (same-wave DS in-order; no block barrier)
        u16* prow = &Psh[w][q16 * 72];
#pragma unroll
        for (int nt = 0; nt < 4; ++nt) {
          u32x2 pk;
          pk.x = cvt_pk_bf16(sc[i2][nt][0], sc[i2][nt][1]);
          pk.y = cvt_pk_bf16(sc[i2][nt][2], sc[i2][nt][3]);
          *(u32x2*)(prow + nt * 16 + g * 4) = pk;
        }
        pf[i2][0] = *(const bf16x8*)(&Psh[w][q16 * 72 + g * 8]);
        pf[i2][1] = *(const bf16x8*)(&Psh[w][q16 * 72 + 32 + g * 8]);
      }

      // ---- PV pair ----
      __builtin_amdgcn_s_setprio(1);
#pragma unroll
      for (int c = 0; c < 2; ++c) {
        int kc = c * 4 + g;
#pragma unroll
        for (int dt = 0; dt < 4; ++dt) {
          int d = dt * 16 + q16;
          bf16x8 vf = *(const bf16x8*)(Vc + d * 64 + ((kc ^ (d & 7)) << 3));
          acc[s0][dt] = __builtin_amdgcn_mfma_f32_16x16x32_bf16(pf[0][c], vf, acc[s0][dt], 0, 0, 0);
          acc[s1][dt] = __builtin_amdgcn_mfma_f32_16x16x32_bf16(pf[1][c], vf, acc[s1][dt], 0, 0, 0);
        }
      }
      __builtin_amdgcn_s_setprio(0);
    }

    __syncthreads();   // drains vmcnt (prefetch landed) + syncs buffer swap
    cur ^= 1;
  }

  // ---- epilogue: rows g*4+r, cols dt*16+q16 ----
#pragma unroll
  for (int s = 0; s < 4; ++s)
#pragma unroll
    for (int r = 0; r < 4; ++r) {
      float linv = 1.0f / __shfl(l_run[s], g * 4 + r, 64);
      size_t orow = (size_t)(b * 2048 + qt * 256 + s * 64 + w * 16 + g * 4 + r);
#pragma unroll
      for (int dt = 0; dt < 4; ++dt)
        out[orow * 2048 + h * 64 + dt * 16 + q16] = f2bf(acc[s][dt][r] * linv);
    }
}

// ---------------- launch ----------------
extern "C" void kernel_launch(void* const* d_in, const int* in_sizes, int n_in,
                              void* d_out, int out_size, void* d_ws, size_t ws_size,
                              hipStream_t stream) {
  const float* x  = (const float*)d_in[0];
  const float* Wq = (const float*)d_in[1];
  const float* bq = (const float*)d_in[2];
  const float* Wk = (const float*)d_in[3];
  const float* bk = (const float*)d_in[4];
  const float* Wv = (const float*)d_in[5];
  const float* bv = (const float*)d_in[6];
  const float* Wo = (const float*)d_in[7];
  const float* bo = (const float*)d_in[8];
  float* out = (float*)d_out;

  char* ws = (char*)d_ws;
  u16*   xb    = (u16*)(ws + 0);               // 4096x2048 bf16 = 16 MB; reused as VT after QKV GEMM
  u16*   wqkvT = (u16*)(ws + 16777216);        // 3072x2048 bf16 = 12 MB
  u16*   woT   = (u16*)(ws + 29360128);        // 2048x2048 bf16 = 8 MB
  float* bqkv  = (float*)(ws + 37748736);      // 3072 f32
  u16*   cqkv  = (u16*)(ws + 37761024);        // 4096x3072 bf16 = 24 MB
  u16*   aout  = (u16*)(ws + 62926848);        // 4096x2048 bf16 = 16 MB
  u16*   vtb   = xb;                           // VT: 16x64x2048 bf16 = 4 MB (xb dead post-GEMM)
  (void)ws_size; (void)in_sizes; (void)n_in; (void)out_size;

  hipMemcpyAsync(bqkv, bq, 2048 * sizeof(float), hipMemcpyDeviceToDevice, stream);
  hipMemcpyAsync(bqkv + 2048, bk, 512 * sizeof(float), hipMemcpyDeviceToDevice, stream);
  hipMemcpyAsync(bqkv + 2560, bv, 512 * sizeof(float), hipMemcpyDeviceToDevice, stream);

  k_conv_bf16<<<4096, 256, 0, stream>>>(x, xb, 1048576);
  dim3 tb(32, 8);
  k_transpose_bf16<<<dim3(64, 64), tb, 0, stream>>>(Wq, wqkvT, 2048, 2048);
  k_transpose_bf16<<<dim3(16, 64), tb, 0, stream>>>(Wk, wqkvT + 2048 * 2048, 2048, 512);
  k_transpose_bf16<<<dim3(16, 64), tb, 0, stream>>>(Wv, wqkvT + 2560 * 2048, 2048, 512);
  k_transpose_bf16<<<dim3(64, 64), tb, 0, stream>>>(Wo, woT, 2048, 2048);

  k_gemm_bt<true><<<768, 256, 0, stream>>>(xb, wqkvT, bqkv, cqkv, 4096, 3072, 2048, 24, 768);
  k_transpose_v<<<dim3(64, 2, 16), tb, 0, stream>>>(cqkv, vtb);
  k_attn<<<dim3(8, 32, 2), 256, 0, stream>>>(cqkv, vtb, aout);
  k_gemm_bt<false><<<512, 256, 0, stream>>>(aout, woT, bo, out, 4096, 2048, 2048, 16, 512);
}

// Round 9
// 369.019 us; speedup vs baseline: 1.3835x; 1.0094x over previous
//
#include <hip/hip_runtime.h>
#include <stdint.h>

typedef unsigned short u16;
typedef unsigned int u32;
typedef short bf16x8 __attribute__((ext_vector_type(8)));
typedef float f32x4 __attribute__((ext_vector_type(4)));
typedef u32 u32x2 __attribute__((ext_vector_type(2)));

#define GLOAD_LDS16(gptr, lptr)                                                \
  __builtin_amdgcn_global_load_lds(                                            \
      (__attribute__((address_space(1))) void*)(gptr),                         \
      (__attribute__((address_space(3))) void*)(lptr), 16, 0, 0)

#define WAITV4() asm volatile("s_waitcnt vmcnt(4)" ::: "memory")
#define WAITV0() asm volatile("s_waitcnt vmcnt(0)" ::: "memory")

#if __has_builtin(__builtin_amdgcn_exp2f)
#define EXP2F(x) __builtin_amdgcn_exp2f(x)
#else
#define EXP2F(x) exp2f(x)
#endif

__device__ __forceinline__ u16 f2bf(float f) {
  union { float f; uint32_t u; } v; v.f = f;
  return (u16)((v.u + 0x7fffu + ((v.u >> 16) & 1u)) >> 16);
}
__device__ __forceinline__ float bf2f(u16 h) {
  union { uint32_t u; float f; } v; v.u = ((uint32_t)h) << 16;
  return v.f;
}
__device__ __forceinline__ u32 cvt_pk_bf16(float lo, float hi) {
  u32 r;
  asm("v_cvt_pk_bf16_f32 %0, %1, %2" : "=v"(r) : "v"(lo), "v"(hi));
  return r;
}

// ---------------- convert x (f32 -> bf16), 8 elems/thread ----------------
__global__ void k_conv_bf16(const float* __restrict__ src, u16* __restrict__ dst, int n8) {
  int i = blockIdx.x * blockDim.x + threadIdx.x;
  if (i >= n8) return;
  const float4* s = (const float4*)src + (size_t)i * 2;
  float4 a = s[0], b = s[1];
  uint4 o;
  o.x = (uint32_t)f2bf(a.x) | ((uint32_t)f2bf(a.y) << 16);
  o.y = (uint32_t)f2bf(a.z) | ((uint32_t)f2bf(a.w) << 16);
  o.z = (uint32_t)f2bf(b.x) | ((uint32_t)f2bf(b.y) << 16);
  o.w = (uint32_t)f2bf(b.z) | ((uint32_t)f2bf(b.w) << 16);
  ((uint4*)dst)[i] = o;
}

// ---------------- transpose f32 [R][C] -> bf16 [C][R] ----------------
__global__ void k_transpose_bf16(const float* __restrict__ src, u16* __restrict__ dst,
                                 int R, int C) {
  __shared__ float tile[32][33];
  int cb = blockIdx.x * 32, rb = blockIdx.y * 32;
  int tx = threadIdx.x, ty = threadIdx.y;
#pragma unroll
  for (int j = 0; j < 4; ++j)
    tile[ty + j * 8][tx] = src[(size_t)(rb + ty + j * 8) * C + cb + tx];
  __syncthreads();
#pragma unroll
  for (int j = 0; j < 4; ++j)
    dst[(size_t)(cb + ty + j * 8) * R + rb + tx] = f2bf(tile[tx][ty + j * 8]);
}

// ---------------- transpose V slice of cqkv -> VT[b*8+kvh][64][2048] (bf16) ----
__global__ void k_transpose_v(const u16* __restrict__ cqkv, u16* __restrict__ vt) {
  __shared__ u16 tile[32][34];
  int st = blockIdx.x, dt = blockIdx.y, bk = blockIdx.z;
  int b = bk >> 3, kvh = bk & 7;
  int tx = threadIdx.x, ty = threadIdx.y;
  const u16* src = cqkv + (size_t)(b * 2048 + st * 32) * 3072 + 2560 + kvh * 64 + dt * 32;
#pragma unroll
  for (int j = 0; j < 4; ++j)
    tile[ty + j * 8][tx] = src[(size_t)(ty + j * 8) * 3072 + tx];
  __syncthreads();
  u16* dst = vt + ((size_t)(bk * 64 + dt * 32)) * 2048 + st * 32;
#pragma unroll
  for (int j = 0; j < 4; ++j)
    dst[(size_t)(ty + j * 8) * 2048 + tx] = tile[tx][ty + j * 8];
}

// ---------------- GEMM v3: 3-buffer counted-vmcnt pipeline, XCD-swizzled ------
// C[M,N] = A[M,K] @ Bt[N,K]^T + bias. 128x128 tile, BK=32, 4 waves.
template <bool BF16OUT>
__global__ __launch_bounds__(256) void k_gemm_bt(
    const u16* __restrict__ A, const u16* __restrict__ Bt,
    const float* __restrict__ bias, void* __restrict__ Cptr,
    int M, int N, int K, int gx, int nwg) {
  __shared__ u16 As[3][128 * 32];
  __shared__ u16 Bs[3][128 * 32];
  const int t = threadIdx.x;
  const int lane = t & 63;
  const int w = t >> 6, wr = w >> 1, wc = w & 1;
  const int bid = blockIdx.x;
  const int cpx = nwg >> 3;
  const int swz = (bid & 7) * cpx + (bid >> 3);
  const int brow = (swz / gx) * 128, bcol = (swz % gx) * 128;
  const int g = lane >> 4, q = lane & 15;

  f32x4 acc[4][4] = {};
  const int srow = t >> 2;            // 0..63
  const int sj = t & 3;
  const int jx = sj ^ ((srow >> 1) & 3);  // same for row srow and srow+64
  const int nkt = K >> 5;

  const u16* gA = A + (size_t)(brow + srow) * K + jx * 8;
  const u16* gB = Bt + (size_t)(bcol + srow) * K + jx * 8;

  auto stage = [&](int bb) {
    GLOAD_LDS16(gA,                     (char*)(&As[bb][0]) + t * 16);
    GLOAD_LDS16(gA + (size_t)64 * K,    (char*)(&As[bb][0]) + 4096 + t * 16);
    GLOAD_LDS16(gB,                     (char*)(&Bs[bb][0]) + t * 16);
    GLOAD_LDS16(gB + (size_t)64 * K,    (char*)(&Bs[bb][0]) + 4096 + t * 16);
    gA += 32; gB += 32;
  };

  stage(0);
  stage(1);
  WAITV4();                     // buffer 0 landed; buffer 1 still in flight
  __builtin_amdgcn_s_barrier();
  __builtin_amdgcn_sched_barrier(0);

  int cur = 0;
  for (int kt = 0; kt < nkt; ++kt) {
    const u16* Ac = As[cur];
    const u16* Bc = Bs[cur];
    bf16x8 a[4], b[4];
#pragma unroll
    for (int mt = 0; mt < 4; ++mt) {
      int row = wr * 64 + mt * 16 + q;
      int pos = g ^ ((row >> 1) & 3);
      a[mt] = *(const bf16x8*)(Ac + row * 32 + pos * 8);
    }
#pragma unroll
    for (int nt = 0; nt < 4; ++nt) {
      int row = wc * 64 + nt * 16 + q;
      int pos = g ^ ((row >> 1) & 3);
      b[nt] = *(const bf16x8*)(Bc + row * 32 + pos * 8);
    }
    if (kt + 2 < nkt) {         // stage kt+2 into the buffer last read at kt-1
      int b2 = cur + 2; if (b2 >= 3) b2 -= 3;
      stage(b2);
    }
    __builtin_amdgcn_s_setprio(1);
#pragma unroll
    for (int mt = 0; mt < 4; ++mt)
#pragma unroll
      for (int nt = 0; nt < 4; ++nt)
        acc[mt][nt] = __builtin_amdgcn_mfma_f32_16x16x32_bf16(a[mt], b[nt], acc[mt][nt], 0, 0, 0);
    __builtin_amdgcn_s_setprio(0);
    if (kt + 1 < nkt) {
      if (kt + 2 < nkt) WAITV4(); else WAITV0();  // next buffer landed; newest 4 stay in flight
      __builtin_amdgcn_s_barrier();
      __builtin_amdgcn_sched_barrier(0);
    }
    ++cur; if (cur >= 3) cur -= 3;
  }
#pragma unroll
  for (int nt = 0; nt < 4; ++nt) {
    int col = bcol + wc * 64 + nt * 16 + q;
    float bv_ = bias[col];
#pragma unroll
    for (int mt = 0; mt < 4; ++mt) {
#pragma unroll
      for (int r = 0; r < 4; ++r) {
        int row = brow + wr * 64 + mt * 16 + g * 4 + r;
        float val = acc[mt][nt][r] + bv_;
        if (BF16OUT)
          ((u16*)Cptr)[(size_t)row * N + col] = f2bf(val);
        else
          ((float*)Cptr)[(size_t)row * N + col] = val;
      }
    }
  }
}

// ---------------- flash attention v8: 4 q-subtiles + counted-vmcnt 3-buffer ----
// Block = 4 waves. Wave w, sub s -> q rows qt*256 + s*64 + w*16 + 0..15.
#define LOG2E 1.44269504088896340736f
__global__ __launch_bounds__(256) void k_attn(const u16* __restrict__ qkv,
                                              const u16* __restrict__ vt,
                                              u16* __restrict__ out) {
  const int qt = blockIdx.x, h = blockIdx.y, b = blockIdx.z;
  const int kvh = h >> 2;
  const int t = threadIdx.x, lane = t & 63, w = t >> 6;
  const int g = lane >> 4, q16 = lane & 15;
  const int LDQ = 3072;

  __shared__ u16 Ksh[3][64 * 64];   // [kv][d], chunk (row,j) holds dc = j ^ (row&7)
  __shared__ u16 Vsh[3][64 * 64];   // [d][kv], chunk (d,j)  holds kc = j ^ (d&7)
  __shared__ u16 Psh[4][16 * 72] __attribute__((aligned(16)));

  // Q fragments, scaled by 1/8 (exact in bf16)
  bf16x8 qf[4][2];
#pragma unroll
  for (int s = 0; s < 4; ++s) {
    const size_t qrow = (size_t)(b * 2048 + qt * 256 + s * 64 + w * 16 + q16);
#pragma unroll
    for (int c = 0; c < 2; ++c) {
      bf16x8 tmp = *(const bf16x8*)(qkv + qrow * LDQ + h * 64 + c * 32 + g * 8);
#pragma unroll
      for (int i = 0; i < 8; ++i)
        tmp[i] = (short)f2bf(bf2f((u16)tmp[i]) * 0.125f);
      qf[s][c] = tmp;
    }
  }

  f32x4 acc[4][4] = {};
  float m_run[4], l_run[4];
#pragma unroll
  for (int s = 0; s < 4; ++s) { m_run[s] = -__builtin_inff(); l_run[s] = 0.f; }

  const int kbase = b * 2048;
  const int koff = 2048 + kvh * 64;
  const u16* vtb = vt + (size_t)((b * 8 + kvh) * 64) * 2048;
  const int srow = t >> 3;  // 0..31
  const int sj = t & 7;
  const int cx = sj ^ (srow & 7);

  const u16* gk = qkv + (size_t)(kbase + srow) * LDQ + koff + cx * 8;
  const u16* gv = vtb + (size_t)srow * 2048 + cx * 8;

  auto stage = [&](int bb) {
    GLOAD_LDS16(gk,               (char*)(&Ksh[bb][0]) + t * 16);
    GLOAD_LDS16(gk + 32 * LDQ,    (char*)(&Ksh[bb][0]) + 4096 + t * 16);
    GLOAD_LDS16(gv,               (char*)(&Vsh[bb][0]) + t * 16);
    GLOAD_LDS16(gv + 32 * 2048,   (char*)(&Vsh[bb][0]) + 4096 + t * 16);
    gk += 64 * LDQ; gv += 64;
  };

  stage(0);
  stage(1);
  WAITV4();
  __builtin_amdgcn_s_barrier();
  __builtin_amdgcn_sched_barrier(0);

  int cur = 0;
  for (int kt = 0; kt < 32; ++kt) {
    if (kt + 2 < 32) {
      int b2 = cur + 2; if (b2 >= 3) b2 -= 3;
      stage(b2);
    }
    const u16* Kc = Ksh[cur];
    const u16* Vc = Vsh[cur];

#pragma unroll
    for (int p2 = 0; p2 < 2; ++p2) {
      const int s0 = p2 * 2, s1 = p2 * 2 + 1;
      // ---- QK^T swapped: sc = mfma(K, Q) -> row = kv (nt*16+g*4+r), col = q16
      f32x4 sc[2][4] = {};
      __builtin_amdgcn_s_setprio(1);
#pragma unroll
      for (int c = 0; c < 2; ++c) {
#pragma unroll
        for (int nt = 0; nt < 4; ++nt) {
          int row = nt * 16 + q16;
          bf16x8 kf = *(const bf16x8*)(Kc + row * 64 + (((c * 4 + g) ^ (row & 7)) << 3));
          sc[0][nt] = __builtin_amdgcn_mfma_f32_16x16x32_bf16(kf, qf[s0][c], sc[0][nt], 0, 0, 0);
          sc[1][nt] = __builtin_amdgcn_mfma_f32_16x16x32_bf16(kf, qf[s1][c], sc[1][nt], 0, 0, 0);
        }
      }
      __builtin_amdgcn_s_setprio(0);

      bf16x8 pf[2][2];
#pragma unroll
      for (int i2 = 0; i2 < 2; ++i2) {
        const int s = p2 * 2 + i2;
        float mt_ = sc[i2][0][0];
#pragma unroll
        for (int nt = 0; nt < 4; ++nt)
#pragma unroll
          for (int r = 0; r < 4; ++r)
            mt_ = fmaxf(mt_, sc[i2][nt][r]);
        mt_ = fmaxf(mt_, __shfl_xor(mt_, 16, 64));
        mt_ = fmaxf(mt_, __shfl_xor(mt_, 32, 64));
        if (__any(mt_ > m_run[s])) {
          float mn = fmaxf(m_run[s], mt_);
          float alpha = EXP2F((m_run[s] - mn) * LOG2E);
          m_run[s] = mn;
          l_run[s] *= alpha;
#pragma unroll
          for (int r = 0; r < 4; ++r) {
            float ar = __shfl(alpha, g * 4 + r, 64);
#pragma unroll
            for (int dt = 0; dt < 4; ++dt) acc[s][dt][r] *= ar;
          }
        }
        float mL = m_run[s] * LOG2E;
        float lt = 0.f;
#pragma unroll
        for (int nt = 0; nt < 4; ++nt)
#pragma unroll
          for (int r = 0; r < 4; ++r) {
            float p_ = EXP2F(fmaf(sc[i2][nt][r], LOG2E, -mL));
            sc[i2][nt][r] = p_;
            lt += p_;
          }
        lt += __shfl_xor(lt, 16, 64);
        lt += __shfl_xor(lt, 32, 64);
        l_run[s] += lt;
        u16* prow = &Psh[w][q16 * 72];
#pragma unroll
        for (int nt = 0; nt < 4; ++nt) {
          u32x2 pk;
          pk.x = cvt_pk_bf16(sc[i2][nt][0], sc[i2][nt][1]);
          pk.y = cvt_pk_bf16(sc[i2][nt][2], sc[i2][nt][3]);
          *(u32x2*)(prow + nt * 16 + g * 4) = pk;
        }
        pf[i2][0] = *(const bf16x8*)(&Psh[w][q16 * 72 + g * 8]);
        pf[i2][1] = *(const bf16x8*)(&Psh[w][q16 * 72 + 32 + g * 8]);
      }

      // ---- PV pair ----
      __builtin_amdgcn_s_setprio(1);
#pragma unroll
      for (int c = 0; c < 2; ++c) {
        int kc = c * 4 + g;
#pragma unroll
        for (int dt = 0; dt < 4; ++dt) {
          int d = dt * 16 + q16;
          bf16x8 vf = *(const bf16x8*)(Vc + d * 64 + ((kc ^ (d & 7)) << 3));
          acc[s0][dt] = __builtin_amdgcn_mfma_f32_16x16x32_bf16(pf[0][c], vf, acc[s0][dt], 0, 0, 0);
          acc[s1][dt] = __builtin_amdgcn_mfma_f32_16x16x32_bf16(pf[1][c], vf, acc[s1][dt], 0, 0, 0);
        }
      }
      __builtin_amdgcn_s_setprio(0);
    }

    if (kt + 1 < 32) {
      if (kt + 2 < 32) WAITV4(); else WAITV0();
      __builtin_amdgcn_s_barrier();
      __builtin_amdgcn_sched_barrier(0);
    }
    ++cur; if (cur >= 3) cur -= 3;
  }

  // ---- epilogue: rows g*4+r, cols dt*16+q16 ----
#pragma unroll
  for (int s = 0; s < 4; ++s)
#pragma unroll
    for (int r = 0; r < 4; ++r) {
      float linv = 1.0f / __shfl(l_run[s], g * 4 + r, 64);
      size_t orow = (size_t)(b * 2048 + qt * 256 + s * 64 + w * 16 + g * 4 + r);
#pragma unroll
      for (int dt = 0; dt < 4; ++dt)
        out[orow * 2048 + h * 64 + dt * 16 + q16] = f2bf(acc[s][dt][r] * linv);
    }
}

// ---------------- launch ----------------
extern "C" void kernel_launch(void* const* d_in, const int* in_sizes, int n_in,
                              void* d_out, int out_size, void* d_ws, size_t ws_size,
                              hipStream_t stream) {
  const float* x  = (const float*)d_in[0];
  const float* Wq = (const float*)d_in[1];
  const float* bq = (const float*)d_in[2];
  const float* Wk = (const float*)d_in[3];
  const float* bk = (const float*)d_in[4];
  const float* Wv = (const float*)d_in[5];
  const float* bv = (const float*)d_in[6];
  const float* Wo = (const float*)d_in[7];
  const float* bo = (const float*)d_in[8];
  float* out = (float*)d_out;

  char* ws = (char*)d_ws;
  u16*   xb    = (u16*)(ws + 0);               // 4096x2048 bf16 = 16 MB; reused as VT after QKV GEMM
  u16*   wqkvT = (u16*)(ws + 16777216);        // 3072x2048 bf16 = 12 MB
  u16*   woT   = (u16*)(ws + 29360128);        // 2048x2048 bf16 = 8 MB
  float* bqkv  = (float*)(ws + 37748736);      // 3072 f32
  u16*   cqkv  = (u16*)(ws + 37761024);        // 4096x3072 bf16 = 24 MB
  u16*   aout  = (u16*)(ws + 62926848);        // 4096x2048 bf16 = 16 MB
  u16*   vtb   = xb;                           // VT: 16x64x2048 bf16 = 4 MB (xb dead post-GEMM)
  (void)ws_size; (void)in_sizes; (void)n_in; (void)out_size;

  hipMemcpyAsync(bqkv, bq, 2048 * sizeof(float), hipMemcpyDeviceToDevice, stream);
  hipMemcpyAsync(bqkv + 2048, bk, 512 * sizeof(float), hipMemcpyDeviceToDevice, stream);
  hipMemcpyAsync(bqkv + 2560, bv, 512 * sizeof(float), hipMemcpyDeviceToDevice, stream);

  k_conv_bf16<<<4096, 256, 0, stream>>>(x, xb, 1048576);
  dim3 tb(32, 8);
  k_transpose_bf16<<<dim3(64, 64), tb, 0, stream>>>(Wq, wqkvT, 2048, 2048);
  k_transpose_bf16<<<dim3(16, 64), tb, 0, stream>>>(Wk, wqkvT + 2048 * 2048, 2048, 512);
  k_transpose_bf16<<<dim3(16, 64), tb, 0, stream>>>(Wv, wqkvT + 2560 * 2048, 2048, 512);
  k_transpose_bf16<<<dim3(64, 64), tb, 0, stream>>>(Wo, woT, 2048, 2048);

  k_gemm_bt<true><<<768, 256, 0, stream>>>(xb, wqkvT, bqkv, cqkv, 4096, 3072, 2048, 24, 768);
  k_transpose_v<<<dim3(64, 2, 16), tb, 0, stream>>>(cqkv, vtb);
  k_attn<<<dim3(8, 32, 2), 256, 0, stream>>>(cqkv, vtb, aout);
  k_gemm_bt<false><<<512, 256, 0, stream>>>(aout, woT, bo, out, 4096, 2048, 2048, 16, 512);
}